// Round 27
// baseline (269.485 us; speedup 1.0000x reference)
//
#include <hip/hip_runtime.h>
#include <math.h>

#define NHD 8
#define HD 32
#define NREF 30
#define RB 4
#define NWIN 144
#define NTOK 64
#define IMG_H (NWIN*NTOK)        /* 9216  */
#define LN_CNT (IMG_H*NREF)      /* 276480 */
#define SCALE 0.1767766952966369f
#define LN_EPS 1e-5f
#define HSTRIDE 972              /* 960 padded: 972%32=12 -> h-slots hit distinct banks */

typedef __attribute__((ext_vector_type(8))) short bf8_t;   // 8 x bf16
typedef __attribute__((ext_vector_type(4))) float f4_t;    // MFMA acc

__device__ __forceinline__ float gelu_f(float v) {
    return 0.5f * v * (1.0f + erff(v * 0.7071067811865476f));
}

__device__ __forceinline__ short f2bf(float f) {           // fp32 -> bf16 RNE
    union { float f; unsigned u; } v; v.f = f;
    unsigned r = v.u + 0x7fffu + ((v.u >> 16) & 1u);
    return (short)(r >> 16);
}

__device__ __forceinline__ float bf2f(unsigned short u) {
    union { unsigned u; float f; } v; v.u = ((unsigned)u) << 16;
    return v.f;
}

// ---- fused prep: cvt(x) | bm | cvt(qkv_w) | cvt(proj_w) | refprep ----
__global__ __launch_bounds__(256) void k_prep(
    const float* __restrict__ x, unsigned short* __restrict__ xb,
    const float* __restrict__ qkv_w, unsigned short* __restrict__ wqb,
    const float* __restrict__ proj_w, unsigned short* __restrict__ wpb,
    const float* __restrict__ mask, const float* __restrict__ bias_table,
    const int* __restrict__ rel_index, float* __restrict__ bmt,
    const float* __restrict__ x_ref, const float* __restrict__ rw,
    const float* __restrict__ rbias, const float* __restrict__ dmu,
    const float* __restrict__ dls, float* __restrict__ ref_q,
    float* __restrict__ ref_v) {
    __shared__ float shbuf[4160 + 1800];   // bm: lm[64][65] + lb[1800]; refprep: 1864
    const int bid = blockIdx.x;
    const int t = threadIdx.x;
    if (bid < 2048) {                      // ---- cvt x (36MB -> 18MB)
        const int n8 = 9437184 / 8;
        for (int i = bid * 256 + t; i < n8; i += 2048 * 256) {
            const float* s = x + (size_t)i * 8;
            float4 a = *reinterpret_cast<const float4*>(s);
            float4 b = *reinterpret_cast<const float4*>(s + 4);
            bf8_t p;
            p[0] = f2bf(a.x); p[1] = f2bf(a.y); p[2] = f2bf(a.z); p[3] = f2bf(a.w);
            p[4] = f2bf(b.x); p[5] = f2bf(b.y); p[6] = f2bf(b.z); p[7] = f2bf(b.w);
            *reinterpret_cast<bf8_t*>(xb + (size_t)i * 8) = p;
        }
    } else if (bid < 2192) {               // ---- bm table (144 blocks, 1/window)
        const int w = bid - 2048;
        float* lm = shbuf;                 // [64][65] transposed-padded mask
        float* lb = shbuf + 4160;          // bias_table copy (225*8)
        for (int u = t; u < 4096; u += 256)
            lm[(u >> 6) * 65 + (u & 63)] = mask[(size_t)w * 4096 + u];
        for (int u = t; u < 1800; u += 256) lb[u] = bias_table[u];
        __syncthreads();
        for (int u = t; u < 4096; u += 256) {
            const int m = u >> 6, n = u & 63;
            const float mv = lm[n * 65 + m];
            const int ri = rel_index[n * 64 + m];
#pragma unroll
            for (int h = 0; h < 8; ++h)
                bmt[(size_t)(w * 8 + h) * 4096 + u] = mv + lb[ri * 8 + h];
        }
    } else if (bid < 2288) {               // ---- cvt qkv_w (96 blocks)
        const int b2 = bid - 2192;
        const int n8 = 196608 / 8;
        for (int i = b2 * 256 + t; i < n8; i += 96 * 256) {
            const float* s = qkv_w + (size_t)i * 8;
            float4 a = *reinterpret_cast<const float4*>(s);
            float4 b = *reinterpret_cast<const float4*>(s + 4);
            bf8_t p;
            p[0] = f2bf(a.x); p[1] = f2bf(a.y); p[2] = f2bf(a.z); p[3] = f2bf(a.w);
            p[4] = f2bf(b.x); p[5] = f2bf(b.y); p[6] = f2bf(b.z); p[7] = f2bf(b.w);
            *reinterpret_cast<bf8_t*>(wqb + (size_t)i * 8) = p;
        }
    } else if (bid < 2320) {               // ---- cvt proj_w (32 blocks)
        const int b2 = bid - 2288;
        const int n8 = 65536 / 8;
        for (int i = b2 * 256 + t; i < n8; i += 32 * 256) {
            const float* s = proj_w + (size_t)i * 8;
            float4 a = *reinterpret_cast<const float4*>(s);
            float4 b = *reinterpret_cast<const float4*>(s + 4);
            bf8_t p;
            p[0] = f2bf(a.x); p[1] = f2bf(a.y); p[2] = f2bf(a.z); p[3] = f2bf(a.w);
            p[4] = f2bf(b.x); p[5] = f2bf(b.y); p[6] = f2bf(b.z); p[7] = f2bf(b.w);
            *reinterpret_cast<bf8_t*>(wpb + (size_t)i * 8) = p;
        }
    } else {                               // ---- refprep (4 blocks)
        float* Wl = shbuf;                 // [60][NREF]
        float* Bl = shbuf + 60 * NREF;     // [60]
        const int rb = bid - 2320;
        for (int i = t; i < 60 * NREF; i += 256) Wl[i] = rw[i];
        if (t < 60) Bl[t] = rbias[t];
        __syncthreads();
        const int d = t;                   // 0..255
        float xr[NREF];
#pragma unroll
        for (int r = 0; r < NREF; ++r) xr[r] = x_ref[(rb * 256 + d) * NREF + r];
        const int h = d >> 5, hd = d & 31;
        const float mu = dmu[d], sg = expf(dls[d]);
        for (int j = 0; j < 60; ++j) {
            float acc = Bl[j];
#pragma unroll
            for (int r = 0; r < NREF; ++r) acc += xr[r] * Wl[j * NREF + r];
            if (j < NREF)
                ref_q[((rb * NHD + h) * NREF + j) * HD + hd] = mu + sg * acc;
            else
                ref_v[((rb * NHD + h) * NREF + (j - NREF)) * HD + hd] = acc;
        }
    }
}

// ------- qkv GEMM via bf16 MFMA: 128x128 tile, BK=64, T14 prefetch ------------
__global__ __launch_bounds__(256) void k_qkv_mfma(
    const unsigned short* __restrict__ xb, const unsigned short* __restrict__ wb,
    const float* __restrict__ bias, unsigned short* __restrict__ qb,
    unsigned short* __restrict__ kb, unsigned short* __restrict__ vb) {
    __shared__ __align__(16) char As[128 * 128];
    __shared__ __align__(16) char Bs[128 * 128];
    const int t = threadIdx.x;
    const int bid = blockIdx.x;
    const int swz = (bid & 7) * (1728 / 8) + (bid >> 3);
    const int r0 = (swz / 6) * 128;
    const int c0 = (swz % 6) * 128;
    const int wid = t >> 6, l = t & 63;
    const int wr = wid >> 1, wc = wid & 1;
    const int lr = l & 15, lg = l >> 4;
    f4_t acc[4][4] = {};
    bf8_t ra[4], rb_[4];
#pragma unroll
    for (int i = 0; i < 4; ++i) {
        const int u = t + 256 * i;
        const int row = u >> 3, c8 = u & 7;
        ra[i]  = *reinterpret_cast<const bf8_t*>(&xb[(size_t)(r0 + row) * 256 + c8 * 8]);
        rb_[i] = *reinterpret_cast<const bf8_t*>(&wb[(size_t)(c0 + row) * 256 + c8 * 8]);
    }
#pragma unroll 1
    for (int ks = 0; ks < 4; ++ks) {
#pragma unroll
        for (int i = 0; i < 4; ++i) {
            const int u = t + 256 * i;
            const int row = u >> 3, c8 = u & 7;
            *reinterpret_cast<bf8_t*>(As + row * 128 + ((c8 * 16) ^ ((row & 7) << 4))) = ra[i];
            *reinterpret_cast<bf8_t*>(Bs + row * 128 + ((c8 * 16) ^ ((row & 7) << 4))) = rb_[i];
        }
        __syncthreads();
        if (ks < 3) {
            const int k0n = (ks + 1) * 64;
#pragma unroll
            for (int i = 0; i < 4; ++i) {
                const int u = t + 256 * i;
                const int row = u >> 3, c8 = u & 7;
                ra[i]  = *reinterpret_cast<const bf8_t*>(&xb[(size_t)(r0 + row) * 256 + k0n + c8 * 8]);
                rb_[i] = *reinterpret_cast<const bf8_t*>(&wb[(size_t)(c0 + row) * 256 + k0n + c8 * 8]);
            }
        }
#pragma unroll
        for (int kk = 0; kk < 2; ++kk) {
            bf8_t a[4], b[4];
#pragma unroll
            for (int mt = 0; mt < 4; ++mt) {
                const int row = wr * 64 + mt * 16 + lr;
                a[mt] = *reinterpret_cast<const bf8_t*>(
                    As + row * 128 + ((kk * 64 + lg * 16) ^ ((row & 7) << 4)));
            }
#pragma unroll
            for (int nt = 0; nt < 4; ++nt) {
                const int row = wc * 64 + nt * 16 + lr;
                b[nt] = *reinterpret_cast<const bf8_t*>(
                    Bs + row * 128 + ((kk * 64 + lg * 16) ^ ((row & 7) << 4)));
            }
#pragma unroll
            for (int mt = 0; mt < 4; ++mt)
#pragma unroll
                for (int nt = 0; nt < 4; ++nt)
                    acc[mt][nt] = __builtin_amdgcn_mfma_f32_16x16x32_bf16(a[mt], b[nt], acc[mt][nt], 0, 0, 0);
        }
        __syncthreads();                   // reads done before next slab's writes
    }
#pragma unroll
    for (int nt = 0; nt < 4; ++nt) {
        const int gc = c0 + wc * 64 + nt * 16 + lr;
        const int i3 = gc >> 8, rem = gc & 255;
        const int h = rem >> 5, hd = rem & 31;
        const float bv = bias[gc];
        unsigned short* dst = (i3 == 0) ? qb : (i3 == 1) ? kb : vb;
#pragma unroll
        for (int mt = 0; mt < 4; ++mt)
#pragma unroll
            for (int j = 0; j < 4; ++j) {
                const int gr = r0 + wr * 64 + mt * 16 + lg * 4 + j;
                const int bb = gr >> 6, n = gr & 63;
                dst[(size_t)((bb * NHD + h) * NTOK + n) * HD + hd] =
                    (unsigned short)f2bf(acc[mt][nt][j] + bv);
            }
    }
}

// ------- proj GEMM via bf16 MFMA: 128x128 tile, BK=64, T14 prefetch -----------
__global__ __launch_bounds__(256) void k_proj_mfma(
    const unsigned short* __restrict__ A, const unsigned short* __restrict__ w,
    const float* __restrict__ bias, float* __restrict__ out) {
    __shared__ __align__(16) char As[128 * 128];
    __shared__ __align__(16) char Bs[128 * 128];
    const int t = threadIdx.x;
    const int bid = blockIdx.x;
    const int swz = (bid & 7) * (576 / 8) + (bid >> 3);
    const int r0 = (swz / 2) * 128;
    const int c0 = (swz % 2) * 128;
    const int wid = t >> 6, l = t & 63;
    const int wr = wid >> 1, wc = wid & 1;
    const int lr = l & 15, lg = l >> 4;
    f4_t acc[4][4] = {};
    bf8_t ra[4], rb_[4];
#pragma unroll
    for (int i = 0; i < 4; ++i) {
        const int u = t + 256 * i;
        const int row = u >> 3, c8 = u & 7;
        ra[i]  = *reinterpret_cast<const bf8_t*>(&A[(size_t)(r0 + row) * 256 + c8 * 8]);
        rb_[i] = *reinterpret_cast<const bf8_t*>(&w[(size_t)(c0 + row) * 256 + c8 * 8]);
    }
#pragma unroll 1
    for (int ks = 0; ks < 4; ++ks) {
#pragma unroll
        for (int i = 0; i < 4; ++i) {
            const int u = t + 256 * i;
            const int row = u >> 3, c8 = u & 7;
            *reinterpret_cast<bf8_t*>(As + row * 128 + ((c8 * 16) ^ ((row & 7) << 4))) = ra[i];
            *reinterpret_cast<bf8_t*>(Bs + row * 128 + ((c8 * 16) ^ ((row & 7) << 4))) = rb_[i];
        }
        __syncthreads();
        if (ks < 3) {
            const int k0n = (ks + 1) * 64;
#pragma unroll
            for (int i = 0; i < 4; ++i) {
                const int u = t + 256 * i;
                const int row = u >> 3, c8 = u & 7;
                ra[i]  = *reinterpret_cast<const bf8_t*>(&A[(size_t)(r0 + row) * 256 + k0n + c8 * 8]);
                rb_[i] = *reinterpret_cast<const bf8_t*>(&w[(size_t)(c0 + row) * 256 + k0n + c8 * 8]);
            }
        }
#pragma unroll
        for (int kk = 0; kk < 2; ++kk) {
            bf8_t a[4], b[4];
#pragma unroll
            for (int mt = 0; mt < 4; ++mt) {
                const int row = wr * 64 + mt * 16 + lr;
                a[mt] = *reinterpret_cast<const bf8_t*>(
                    As + row * 128 + ((kk * 64 + lg * 16) ^ ((row & 7) << 4)));
            }
#pragma unroll
            for (int nt = 0; nt < 4; ++nt) {
                const int row = wc * 64 + nt * 16 + lr;
                b[nt] = *reinterpret_cast<const bf8_t*>(
                    Bs + row * 128 + ((kk * 64 + lg * 16) ^ ((row & 7) << 4)));
            }
#pragma unroll
            for (int mt = 0; mt < 4; ++mt)
#pragma unroll
                for (int nt = 0; nt < 4; ++nt)
                    acc[mt][nt] = __builtin_amdgcn_mfma_f32_16x16x32_bf16(a[mt], b[nt], acc[mt][nt], 0, 0, 0);
        }
        __syncthreads();
    }
#pragma unroll
    for (int nt = 0; nt < 4; ++nt) {
        const int gc = c0 + wc * 64 + nt * 16 + lr;
        const float bv = bias[gc];
#pragma unroll
        for (int mt = 0; mt < 4; ++mt)
#pragma unroll
            for (int j = 0; j < 4; ++j) {
                const int gr = r0 + wr * 64 + mt * 16 + lg * 4 + j;
                out[(size_t)gr * 256 + gc] = acc[mt][nt][j] + bv;
            }
    }
}

// -------- ref scores, 1 block/window (all 8 h): q(bf16) . ref_q ---------------
// rs h-stride padded to 972 floats (972%32=12): conflict-free h-slots.
__global__ __launch_bounds__(256) void k_scores(
    const unsigned short* __restrict__ qbuf, const float* __restrict__ ref_q,
    float* __restrict__ scores) {
    const int bid = blockIdx.x;            // rb*NWIN + w
    const int w = bid % NWIN, rb = bid / NWIN;
    __shared__ __align__(16) float rs[8 * HSTRIDE];
    const int t = threadIdx.x;
    for (int u = t; u < 1920; u += 256) {
        const int off = u * 4;
        const int h = off / 960, rem = off % 960;
        *reinterpret_cast<float4*>(&rs[h * HSTRIDE + rem]) =
            *reinterpret_cast<const float4*>(&ref_q[(size_t)rb * 7680 + off]);
    }
    __syncthreads();
    const int h = t & 7, nb = t >> 3;      // nb 0..31
    const float* rsh = &rs[h * HSTRIDE];
#pragma unroll 1
    for (int half = 0; half < 2; ++half) {
        const int n = half * 32 + nb;
        const unsigned short* qsrc =
            &qbuf[(size_t)(((rb * NWIN + w) * NHD) + h) * 2048 + n * 32];
        float q[32];
#pragma unroll
        for (int c8 = 0; c8 < 4; ++c8) {
            bf8_t v = *reinterpret_cast<const bf8_t*>(&qsrc[c8 * 8]);
#pragma unroll
            for (int j = 0; j < 8; ++j)
                q[c8 * 8 + j] = bf2f((unsigned short)v[j]);
        }
        float* dst = &scores[((size_t)(rb * IMG_H + w * 64 + n) * NREF) * NHD + h];
        for (int r = 0; r < NREF; ++r) {
            float acc = 0.f;
#pragma unroll
            for (int d = 0; d < 32; ++d) acc += q[d] * rsh[r * 32 + d];
            dst[r * NHD] = acc;
        }
    }
}

// ---------------- conv 3x3 via MFMA (implicit GEMM), 32-row chunks ------------
// CHANNEL-LAST sc/upd: pixel (y,x) owns 8 contiguous channels.
template<int FUSED>
__global__ __launch_bounds__(256) void k_conv_mfma(
    const float* __restrict__ scPrev, const unsigned short* __restrict__ updPrev,
    const float* __restrict__ stPrev, const float* __restrict__ conv_w,
    const float* __restrict__ conv_b, float* __restrict__ scOut,
    unsigned short* __restrict__ updOut, float* __restrict__ stats) {
    const int bid = blockIdx.x;            // rb*288 + ychunk
    const int rb = bid / 288;
    const int y0 = (bid % 288) * 32;
    __shared__ __align__(16) unsigned short At[34][32][8];
    __shared__ float red[4][8][2];
    __shared__ float lmean[8], lrsig[8];
    const int t = threadIdx.x;
    if (FUSED) {
        if (t < 8) {
            const float s0 = stPrev[(rb * NHD + t) * 2];
            const float s1 = stPrev[(rb * NHD + t) * 2 + 1];
            const float m = s0 * (1.f / LN_CNT);
            const float v = s1 * (1.f / LN_CNT) - m * m;
            lmean[t] = m;
            lrsig[t] = rsqrtf(v + LN_EPS);
        }
        __syncthreads();
    }
    // zero pad columns sx = 0 and 31
    for (int f = t; f < 34 * 2; f += 256) {
        const int yy = f >> 1, side = (f & 1) ? 31 : 0;
        bf8_t z;
#pragma unroll
        for (int j = 0; j < 8; ++j) z[j] = 0;
        *reinterpret_cast<bf8_t*>(&At[yy][side][0]) = z;
    }
    // stage: pixel (yy, xc) -> 8 contiguous channels (32B) -> one b128 write
    for (int ps = t; ps < 34 * 30; ps += 256) {
        const int yy = ps / 30, xc = ps % 30;
        const int y = y0 - 1 + yy;
        bf8_t pk;
#pragma unroll
        for (int j = 0; j < 8; ++j) pk[j] = 0;
        if (y >= 0 && y < IMG_H) {
            const size_t idx = ((size_t)(rb * IMG_H + y) * NREF + xc) * NHD;
            float4 s0 = *reinterpret_cast<const float4*>(&scPrev[idx]);
            float4 s1 = *reinterpret_cast<const float4*>(&scPrev[idx + 4]);
            float a[8] = {s0.x, s0.y, s0.z, s0.w, s1.x, s1.y, s1.z, s1.w};
            if (FUSED) {
                bf8_t u8 = *reinterpret_cast<const bf8_t*>(&updPrev[idx]);
#pragma unroll
                for (int ci = 0; ci < 8; ++ci)
                    a[ci] += gelu_f((bf2f((unsigned short)u8[ci]) - lmean[ci]) * lrsig[ci]);
                if (yy >= 1 && yy <= 32) {
                    float4 o0, o1;
                    o0.x = a[0]; o0.y = a[1]; o0.z = a[2]; o0.w = a[3];
                    o1.x = a[4]; o1.y = a[5]; o1.z = a[6]; o1.w = a[7];
                    *reinterpret_cast<float4*>(&scOut[idx]) = o0;
                    *reinterpret_cast<float4*>(&scOut[idx + 4]) = o1;
                }
            }
#pragma unroll
            for (int ci = 0; ci < 8; ++ci) pk[ci] = f2bf(a[ci]);
        }
        *reinterpret_cast<bf8_t*>(&At[yy][xc + 1][0]) = pk;
    }
    // weight B-fragments: lane (lr=co, lg) holds k-slice [tap=kg*4+lg][ci 0..7]
    const int l = t & 63, wv = t >> 6;
    const int lr = l & 15, lg = l >> 4;
    bf8_t wf[3];
#pragma unroll
    for (int kg = 0; kg < 3; ++kg) {
        const int tap = kg * 4 + lg;
        bf8_t wq;
#pragma unroll
        for (int j = 0; j < 8; ++j) wq[j] = 0;
        if (lr < 8 && tap < 9) {
            const int dy = tap / 3, dx = tap % 3;
#pragma unroll
            for (int ci = 0; ci < 8; ++ci)
                wq[ci] = f2bf(conv_w[lr * 72 + ci * 9 + dy * 3 + dx]);
        }
        wf[kg] = wq;
    }
    const float cb = (lr < 8) ? conv_b[lr] : 0.f;
    __syncthreads();
    float ls = 0.f, lss = 0.f;
    // 60 M-tiles of 16 pixels; wave wv owns tiles [wv*15, wv*15+15)
#pragma unroll 1
    for (int ti = 0; ti < 15; ++ti) {
        const int tile = wv * 15 + ti;
        const int pA = tile * 16 + lr;     // A-side pixel for this lane
        const int ylA = pA / 30, xA = pA % 30;
        f4_t o;
        o[0] = cb; o[1] = cb; o[2] = cb; o[3] = cb;
#pragma unroll
        for (int kg = 0; kg < 3; ++kg) {
            const int tap = kg * 4 + lg;
            const int dy = (tap < 9) ? tap / 3 : 0;
            const int dx = (tap < 9) ? tap % 3 : 0;
            bf8_t a = *reinterpret_cast<const bf8_t*>(&At[ylA + dy][xA + dx][0]);
            o = __builtin_amdgcn_mfma_f32_16x16x32_bf16(a, wf[kg], o, 0, 0, 0);
        }
        if (lr < 8) {
#pragma unroll
            for (int j = 0; j < 4; ++j) {
                const int pD = tile * 16 + lg * 4 + j;
                const int yl = pD / 30, x = pD % 30;
                updOut[((size_t)(rb * IMG_H + y0 + yl) * NREF + x) * NHD + lr] =
                    (unsigned short)f2bf(o[j]);
                ls += o[j];
                lss += o[j] * o[j];
            }
        }
    }
    ls += __shfl_xor(ls, 16); ls += __shfl_xor(ls, 32);
    lss += __shfl_xor(lss, 16); lss += __shfl_xor(lss, 32);
    if (l < 8) { red[wv][l][0] = ls; red[wv][l][1] = lss; }
    __syncthreads();
    if (t < 8) {
        atomicAdd(&stats[(rb * NHD + t) * 2],
                  red[0][t][0] + red[1][t][0] + red[2][t][0] + red[3][t][0]);
        atomicAdd(&stats[(rb * NHD + t) * 2 + 1],
                  red[0][t][1] + red[1][t][1] + red[2][t][1] + red[3][t][1]);
    }
}

// --- softmax over NREF (fused final LN+gelu+residual), half-window blocks -----
// Single gelu pass: val cached in a PRIVATE per-thread LDS strip val[t*31+r]
// (stride 31 -> bank (r-t)%32, 2 lanes/bank = free; same-thread RW, no sync).
// Kills the round-26 duplicate gelu+loads (VALUBusy 54% @ 48us).
__global__ __launch_bounds__(256) void k_qnewf(
    const float* __restrict__ scores, const unsigned short* __restrict__ upd,
    const float* __restrict__ st, const float* __restrict__ ref_v,
    unsigned short* __restrict__ qbuf) {
    const int bid = blockIdx.x;            // (rb*NWIN + w)*2 + half
    const int half = bid & 1;
    const int wwin = (bid >> 1) % NWIN, rb = (bid >> 1) / NWIN;
    __shared__ __align__(16) float rv[8 * HSTRIDE];
    __shared__ float val[256 * 31];
    __shared__ float lmean[8], lrsig[8];
    const int t = threadIdx.x;
    if (t < 8) {
        const float s0 = st[(rb * NHD + t) * 2];
        const float s1 = st[(rb * NHD + t) * 2 + 1];
        const float m = s0 * (1.f / LN_CNT);
        const float v = s1 * (1.f / LN_CNT) - m * m;
        lmean[t] = m;
        lrsig[t] = rsqrtf(v + LN_EPS);
    }
    for (int u = t; u < 1920; u += 256) {
        const int off = u * 4;
        const int hh = off / 960, rem = off % 960;
        *reinterpret_cast<float4*>(&rv[hh * HSTRIDE + rem]) =
            *reinterpret_cast<const float4*>(&ref_v[(size_t)rb * 7680 + off]);
    }
    __syncthreads();
    const int h = t & 7, nb = t >> 3;
    const float lm = lmean[h], lr_ = lrsig[h];
    const float* rvh = &rv[h * HSTRIDE];
    float* vt = &val[t * 31];
    const int n = half * 32 + nb;
    const size_t base = ((size_t)(rb * IMG_H + wwin * 64 + n) * NREF) * NHD + h;
    // pass 1: compute val once, cache in LDS, track max
    float mx = -1e30f;
#pragma unroll 6
    for (int r = 0; r < NREF; ++r) {
        const float uv = bf2f(upd[base + r * NHD]);
        const float v = scores[base + r * NHD] + gelu_f((uv - lm) * lr_);
        vt[r] = v;
        mx = fmaxf(mx, v);
    }
    // pass 2: exp + accumulate from LDS
    float sum = 0.f;
    float acc[32] = {0.f};
#pragma unroll 2
    for (int r = 0; r < NREF; ++r) {
        const float e = expf(vt[r] - mx);
        sum += e;
#pragma unroll
        for (int d = 0; d < 32; ++d) acc[d] += e * rvh[r * 32 + d];
    }
    const float inv = SCALE / sum;
    unsigned short* dst =
        &qbuf[(size_t)(((rb * NWIN + wwin) * NHD) + h) * 2048 + n * 32];
#pragma unroll
    for (int c8 = 0; c8 < 4; ++c8) {
        bf8_t pk;
#pragma unroll
        for (int j = 0; j < 8; ++j) pk[j] = f2bf(acc[c8 * 8 + j] * inv);
        *reinterpret_cast<bf8_t*>(&dst[c8 * 8]) = pk;
    }
}

// ---------------- window attention via MFMA, swapped operands ----------------
__global__ __launch_bounds__(256, 4) void k_wattn_mfma(
    const unsigned short* __restrict__ qbuf, const unsigned short* __restrict__ kbuf,
    const unsigned short* __restrict__ vbuf, const float* __restrict__ bmt,
    unsigned short* __restrict__ pre) {
    const int wh = blockIdx.x;             // w*8 + h
    const int w = wh >> 3, h = wh & 7;
    const int t = threadIdx.x;
    const int rb = t >> 6;                 // wave id = rb
    const int l = t & 63;
    const int lr = l & 15, lg = l >> 4;
    const int b = rb * NWIN + w;
    const int bid = b * NHD + h;
    __shared__ __align__(16) char P[4][64 * 128];

    // ---- C init from bmt[w][h][m][n]
    f4_t acc[4][4];
    const float* bm = &bmt[(size_t)wh * 4096];
#pragma unroll
    for (int mt = 0; mt < 4; ++mt)
#pragma unroll
        for (int nt = 0; nt < 4; ++nt)
#pragma unroll
            for (int j = 0; j < 4; ++j)
                acc[mt][nt][j] = bm[(mt * 16 + lg * 4 + j) * 64 + nt * 16 + lr];

    // ---- K frags (A) and Q frags (B): both bf16, 8 contiguous
    const unsigned short* kp = &kbuf[(size_t)bid * 2048];
    const unsigned short* qp = &qbuf[(size_t)bid * 2048];
    bf8_t kf[4], qf[4];
#pragma unroll
    for (int mt = 0; mt < 4; ++mt) {
        kf[mt] = *reinterpret_cast<const bf8_t*>(&kp[(mt * 16 + lr) * 32 + lg * 8]);
        qf[mt] = *reinterpret_cast<const bf8_t*>(&qp[(mt * 16 + lr) * 32 + lg * 8]);
    }
    // ---- S^T[m][n] = sum_k k[m][kk] q[n][kk] + bm
#pragma unroll
    for (int mt = 0; mt < 4; ++mt)
#pragma unroll
        for (int nt = 0; nt < 4; ++nt)
            acc[mt][nt] = __builtin_amdgcn_mfma_f32_16x16x32_bf16(kf[mt], qf[nt], acc[mt][nt], 0, 0, 0);

    // ---- softmax over m (in-lane mt,j + shfl over lg)
#pragma unroll
    for (int nt = 0; nt < 4; ++nt) {
        float mx = -1e30f;
#pragma unroll
        for (int mt = 0; mt < 4; ++mt)
#pragma unroll
            for (int j = 0; j < 4; ++j) mx = fmaxf(mx, acc[mt][nt][j]);
        mx = fmaxf(mx, __shfl_xor(mx, 16));
        mx = fmaxf(mx, __shfl_xor(mx, 32));
        float s = 0.f;
#pragma unroll
        for (int mt = 0; mt < 4; ++mt)
#pragma unroll
            for (int j = 0; j < 4; ++j) {
                const float e = expf(acc[mt][nt][j] - mx);
                acc[mt][nt][j] = e;
                s += e;
            }
        s += __shfl_xor(s, 16);
        s += __shfl_xor(s, 32);
        const float inv = 1.f / s;
#pragma unroll
        for (int mt = 0; mt < 4; ++mt)
#pragma unroll
            for (int j = 0; j < 4; ++j) acc[mt][nt][j] *= inv;
    }

    // ---- pack P[n][m] bf16 into LDS (row 128B, XOR ((n&7)<<4))
    const int n7 = (lr & 7) << 4;
    char* Pw = P[rb];
#pragma unroll
    for (int nt = 0; nt < 4; ++nt) {
        const int rowb = (nt * 16 + lr) * 128;
#pragma unroll
        for (int mt = 0; mt < 4; ++mt)
#pragma unroll
            for (int jp = 0; jp < 2; ++jp) {
                const unsigned lo = (unsigned short)f2bf(acc[mt][nt][jp * 2]);
                const unsigned hi = (unsigned short)f2bf(acc[mt][nt][jp * 2 + 1]);
                const int mb = (mt * 16 + lg * 4 + jp * 2) * 2;
                *reinterpret_cast<unsigned*>(&Pw[rowb + (mb ^ n7)]) = lo | (hi << 16);
            }
    }
    __syncthreads();

    // ---- V^T frags (A): row hd, k = m (gather u16)
    const unsigned short* vp = &vbuf[(size_t)bid * 2048];
    bf8_t vf[2][2];
#pragma unroll
    for (int ht = 0; ht < 2; ++ht)
#pragma unroll
        for (int ks = 0; ks < 2; ++ks) {
            bf8_t tv;
#pragma unroll
            for (int j = 0; j < 8; ++j)
                tv[j] = (short)vp[(ks * 32 + lg * 8 + j) * 32 + ht * 16 + lr];
            vf[ht][ks] = tv;
        }

    // ---- O^T = V^T @ P^T
    f4_t o[2][4] = {};
#pragma unroll
    for (int ks = 0; ks < 2; ++ks)
#pragma unroll
        for (int nt = 0; nt < 4; ++nt) {
            const int rowb = (nt * 16 + lr) * 128;
            bf8_t pf = *reinterpret_cast<const bf8_t*>(&Pw[rowb + ((ks * 64 + lg * 16) ^ n7)]);
#pragma unroll
            for (int ht = 0; ht < 2; ++ht)
                o[ht][nt] = __builtin_amdgcn_mfma_f32_16x16x32_bf16(vf[ht][ks], pf, o[ht][nt], 0, 0, 0);
        }

    // ---- store O^T as bf16: pre[(b*64+n)*256 + h*32 + hd]
#pragma unroll
    for (int ht = 0; ht < 2; ++ht)
#pragma unroll
        for (int nt = 0; nt < 4; ++nt) {
            ushort4 pk;
            pk.x = (unsigned short)f2bf(o[ht][nt][0]);
            pk.y = (unsigned short)f2bf(o[ht][nt][1]);
            pk.z = (unsigned short)f2bf(o[ht][nt][2]);
            pk.w = (unsigned short)f2bf(o[ht][nt][3]);
            const int n = nt * 16 + lr;
            const int hd = ht * 16 + lg * 4;
            *reinterpret_cast<ushort4*>(&pre[(size_t)(b * 64 + n) * 256 + h * 32 + hd]) = pk;
        }
}

extern "C" void kernel_launch(void* const* d_in, const int* in_sizes, int n_in,
                              void* d_out, int out_size, void* d_ws, size_t ws_size,
                              hipStream_t stream) {
    const float* x          = (const float*)d_in[0];
    const float* mask       = (const float*)d_in[1];
    const float* x_ref      = (const float*)d_in[2];
    const float* qkv_w      = (const float*)d_in[3];
    const float* qkv_b      = (const float*)d_in[4];
    const float* proj_w     = (const float*)d_in[5];
    const float* proj_b     = (const float*)d_in[6];
    const float* bias_table = (const float*)d_in[7];
    const float* diff_mu    = (const float*)d_in[8];
    const float* diff_ls    = (const float*)d_in[9];
    const float* ref_qk_w   = (const float*)d_in[10];
    const float* ref_qk_b   = (const float*)d_in[11];
    const float* conv_w     = (const float*)d_in[12];
    const float* conv_b     = (const float*)d_in[13];
    const int*   rel_index  = (const int*)d_in[14];
    float* out = (float*)d_out;

    unsigned short* xb   = (unsigned short*)d_ws;                // 9437184 u16
    unsigned short* qb16 = xb + 9437184;                         // 9437184 u16
    unsigned short* kb16 = qb16 + 9437184;                       // 9437184 u16
    unsigned short* vb16 = kb16 + 9437184;                       // 9437184 u16
    float* scA           = (float*)(vb16 + 9437184);             // 8847360 f
    unsigned short* updA = (unsigned short*)(scA + 8847360);     // 8847360 u16
    unsigned short* updB = updA + 8847360;                       // 8847360 u16
    float* rq            = (float*)(updB + 8847360);             // 30720 f
    float* rv            = rq + 30720;                           // 30720 f
    float* st            = rv + 30720;                           // 192 f (3 x 64)
    float* bmt           = st + 192;                             // 4718592 f
    unsigned short* wqb  = (unsigned short*)(bmt + 4718592);     // 196608 u16
    unsigned short* wpb  = wqb + 196608;                         // 65536 u16
    float* scB           = (float*)d_ws;                         // reuses xb+qb16 (dead during conv)
    unsigned short* pre  = (unsigned short*)scA;                 // alias: scA dead after k_qnewf

    k_prep<<<2324, 256, 0, stream>>>(x, xb, qkv_w, wqb, proj_w, wpb,
                                     mask, bias_table, rel_index, bmt,
                                     x_ref, ref_qk_w, ref_qk_b, diff_mu, diff_ls,
                                     rq, rv);
    k_qkv_mfma<<<1728, 256, 0, stream>>>(xb, wqb, qkv_b, qb16, kb16, vb16);
    k_scores<<<RB * NWIN, 256, 0, stream>>>(qb16, rq, scA);
    hipMemsetAsync(st, 0, 192 * sizeof(float), stream);
    k_conv_mfma<0><<<RB * 288, 256, 0, stream>>>(scA, updA, st, conv_w, conv_b, scB, updA, st);
    k_conv_mfma<1><<<RB * 288, 256, 0, stream>>>(scA, updA, st, conv_w, conv_b, scB, updB, st + 64);
    k_conv_mfma<1><<<RB * 288, 256, 0, stream>>>(scB, updB, st + 64, conv_w, conv_b, scA, updA, st + 128);
    k_qnewf<<<RB * NWIN * 2, 256, 0, stream>>>(scA, updA, st + 128, rv, qb16);
    k_wattn_mfma<<<NWIN * NHD, 256, 0, stream>>>(qb16, kb16, vb16, bmt, pre);
    k_proj_mfma<<<576, 256, 0, stream>>>(pre, wpb, proj_b, out);
}

// Round 28
// 256.874 us; speedup vs baseline: 1.0491x; 1.0491x over previous
//
#include <hip/hip_runtime.h>
#include <math.h>

#define NHD 8
#define HD 32
#define NREF 30
#define RB 4
#define NWIN 144
#define NTOK 64
#define IMG_H (NWIN*NTOK)        /* 9216  */
#define LN_CNT (IMG_H*NREF)      /* 276480 */
#define SCALE 0.1767766952966369f
#define LN_EPS 1e-5f
#define HSTRIDE 972              /* 960 padded: 972%32=12 -> h-slots hit distinct banks */

typedef __attribute__((ext_vector_type(8))) short bf8_t;   // 8 x bf16
typedef __attribute__((ext_vector_type(4))) float f4_t;    // MFMA acc

__device__ __forceinline__ float gelu_f(float v) {
    return 0.5f * v * (1.0f + erff(v * 0.7071067811865476f));
}

__device__ __forceinline__ short f2bf(float f) {           // fp32 -> bf16 RNE
    union { float f; unsigned u; } v; v.f = f;
    unsigned r = v.u + 0x7fffu + ((v.u >> 16) & 1u);
    return (short)(r >> 16);
}

__device__ __forceinline__ float bf2f(unsigned short u) {
    union { unsigned u; float f; } v; v.u = ((unsigned)u) << 16;
    return v.f;
}

// ---- fused prep: cvt(x) | bm | cvt(qkv_w) | cvt(proj_w) | refprep ----
__global__ __launch_bounds__(256) void k_prep(
    const float* __restrict__ x, unsigned short* __restrict__ xb,
    const float* __restrict__ qkv_w, unsigned short* __restrict__ wqb,
    const float* __restrict__ proj_w, unsigned short* __restrict__ wpb,
    const float* __restrict__ mask, const float* __restrict__ bias_table,
    const int* __restrict__ rel_index, float* __restrict__ bmt,
    const float* __restrict__ x_ref, const float* __restrict__ rw,
    const float* __restrict__ rbias, const float* __restrict__ dmu,
    const float* __restrict__ dls, float* __restrict__ ref_q,
    float* __restrict__ ref_v) {
    __shared__ float shbuf[4160 + 1800];   // bm: lm[64][65] + lb[1800]; refprep: 1864
    const int bid = blockIdx.x;
    const int t = threadIdx.x;
    if (bid < 2048) {                      // ---- cvt x (36MB -> 18MB)
        const int n8 = 9437184 / 8;
        for (int i = bid * 256 + t; i < n8; i += 2048 * 256) {
            const float* s = x + (size_t)i * 8;
            float4 a = *reinterpret_cast<const float4*>(s);
            float4 b = *reinterpret_cast<const float4*>(s + 4);
            bf8_t p;
            p[0] = f2bf(a.x); p[1] = f2bf(a.y); p[2] = f2bf(a.z); p[3] = f2bf(a.w);
            p[4] = f2bf(b.x); p[5] = f2bf(b.y); p[6] = f2bf(b.z); p[7] = f2bf(b.w);
            *reinterpret_cast<bf8_t*>(xb + (size_t)i * 8) = p;
        }
    } else if (bid < 2192) {               // ---- bm table (144 blocks, 1/window)
        const int w = bid - 2048;
        float* lm = shbuf;                 // [64][65] transposed-padded mask
        float* lb = shbuf + 4160;          // bias_table copy (225*8)
        for (int u = t; u < 4096; u += 256)
            lm[(u >> 6) * 65 + (u & 63)] = mask[(size_t)w * 4096 + u];
        for (int u = t; u < 1800; u += 256) lb[u] = bias_table[u];
        __syncthreads();
        for (int u = t; u < 4096; u += 256) {
            const int m = u >> 6, n = u & 63;
            const float mv = lm[n * 65 + m];
            const int ri = rel_index[n * 64 + m];
#pragma unroll
            for (int h = 0; h < 8; ++h)
                bmt[(size_t)(w * 8 + h) * 4096 + u] = mv + lb[ri * 8 + h];
        }
    } else if (bid < 2288) {               // ---- cvt qkv_w (96 blocks)
        const int b2 = bid - 2192;
        const int n8 = 196608 / 8;
        for (int i = b2 * 256 + t; i < n8; i += 96 * 256) {
            const float* s = qkv_w + (size_t)i * 8;
            float4 a = *reinterpret_cast<const float4*>(s);
            float4 b = *reinterpret_cast<const float4*>(s + 4);
            bf8_t p;
            p[0] = f2bf(a.x); p[1] = f2bf(a.y); p[2] = f2bf(a.z); p[3] = f2bf(a.w);
            p[4] = f2bf(b.x); p[5] = f2bf(b.y); p[6] = f2bf(b.z); p[7] = f2bf(b.w);
            *reinterpret_cast<bf8_t*>(wqb + (size_t)i * 8) = p;
        }
    } else if (bid < 2320) {               // ---- cvt proj_w (32 blocks)
        const int b2 = bid - 2288;
        const int n8 = 65536 / 8;
        for (int i = b2 * 256 + t; i < n8; i += 32 * 256) {
            const float* s = proj_w + (size_t)i * 8;
            float4 a = *reinterpret_cast<const float4*>(s);
            float4 b = *reinterpret_cast<const float4*>(s + 4);
            bf8_t p;
            p[0] = f2bf(a.x); p[1] = f2bf(a.y); p[2] = f2bf(a.z); p[3] = f2bf(a.w);
            p[4] = f2bf(b.x); p[5] = f2bf(b.y); p[6] = f2bf(b.z); p[7] = f2bf(b.w);
            *reinterpret_cast<bf8_t*>(wpb + (size_t)i * 8) = p;
        }
    } else {                               // ---- refprep (4 blocks)
        float* Wl = shbuf;                 // [60][NREF]
        float* Bl = shbuf + 60 * NREF;     // [60]
        const int rb = bid - 2320;
        for (int i = t; i < 60 * NREF; i += 256) Wl[i] = rw[i];
        if (t < 60) Bl[t] = rbias[t];
        __syncthreads();
        const int d = t;                   // 0..255
        float xr[NREF];
#pragma unroll
        for (int r = 0; r < NREF; ++r) xr[r] = x_ref[(rb * 256 + d) * NREF + r];
        const int h = d >> 5, hd = d & 31;
        const float mu = dmu[d], sg = expf(dls[d]);
        for (int j = 0; j < 60; ++j) {
            float acc = Bl[j];
#pragma unroll
            for (int r = 0; r < NREF; ++r) acc += xr[r] * Wl[j * NREF + r];
            if (j < NREF)
                ref_q[((rb * NHD + h) * NREF + j) * HD + hd] = mu + sg * acc;
            else
                ref_v[((rb * NHD + h) * NREF + (j - NREF)) * HD + hd] = acc;
        }
    }
}

// ------- qkv GEMM via bf16 MFMA: 128x128 tile, BK=64, T14 prefetch ------------
__global__ __launch_bounds__(256) void k_qkv_mfma(
    const unsigned short* __restrict__ xb, const unsigned short* __restrict__ wb,
    const float* __restrict__ bias, unsigned short* __restrict__ qb,
    unsigned short* __restrict__ kb, unsigned short* __restrict__ vb) {
    __shared__ __align__(16) char As[128 * 128];
    __shared__ __align__(16) char Bs[128 * 128];
    const int t = threadIdx.x;
    const int bid = blockIdx.x;
    const int swz = (bid & 7) * (1728 / 8) + (bid >> 3);
    const int r0 = (swz / 6) * 128;
    const int c0 = (swz % 6) * 128;
    const int wid = t >> 6, l = t & 63;
    const int wr = wid >> 1, wc = wid & 1;
    const int lr = l & 15, lg = l >> 4;
    f4_t acc[4][4] = {};
    bf8_t ra[4], rb_[4];
#pragma unroll
    for (int i = 0; i < 4; ++i) {
        const int u = t + 256 * i;
        const int row = u >> 3, c8 = u & 7;
        ra[i]  = *reinterpret_cast<const bf8_t*>(&xb[(size_t)(r0 + row) * 256 + c8 * 8]);
        rb_[i] = *reinterpret_cast<const bf8_t*>(&wb[(size_t)(c0 + row) * 256 + c8 * 8]);
    }
#pragma unroll 1
    for (int ks = 0; ks < 4; ++ks) {
#pragma unroll
        for (int i = 0; i < 4; ++i) {
            const int u = t + 256 * i;
            const int row = u >> 3, c8 = u & 7;
            *reinterpret_cast<bf8_t*>(As + row * 128 + ((c8 * 16) ^ ((row & 7) << 4))) = ra[i];
            *reinterpret_cast<bf8_t*>(Bs + row * 128 + ((c8 * 16) ^ ((row & 7) << 4))) = rb_[i];
        }
        __syncthreads();
        if (ks < 3) {
            const int k0n = (ks + 1) * 64;
#pragma unroll
            for (int i = 0; i < 4; ++i) {
                const int u = t + 256 * i;
                const int row = u >> 3, c8 = u & 7;
                ra[i]  = *reinterpret_cast<const bf8_t*>(&xb[(size_t)(r0 + row) * 256 + k0n + c8 * 8]);
                rb_[i] = *reinterpret_cast<const bf8_t*>(&wb[(size_t)(c0 + row) * 256 + k0n + c8 * 8]);
            }
        }
#pragma unroll
        for (int kk = 0; kk < 2; ++kk) {
            bf8_t a[4], b[4];
#pragma unroll
            for (int mt = 0; mt < 4; ++mt) {
                const int row = wr * 64 + mt * 16 + lr;
                a[mt] = *reinterpret_cast<const bf8_t*>(
                    As + row * 128 + ((kk * 64 + lg * 16) ^ ((row & 7) << 4)));
            }
#pragma unroll
            for (int nt = 0; nt < 4; ++nt) {
                const int row = wc * 64 + nt * 16 + lr;
                b[nt] = *reinterpret_cast<const bf8_t*>(
                    Bs + row * 128 + ((kk * 64 + lg * 16) ^ ((row & 7) << 4)));
            }
#pragma unroll
            for (int mt = 0; mt < 4; ++mt)
#pragma unroll
                for (int nt = 0; nt < 4; ++nt)
                    acc[mt][nt] = __builtin_amdgcn_mfma_f32_16x16x32_bf16(a[mt], b[nt], acc[mt][nt], 0, 0, 0);
        }
        __syncthreads();                   // reads done before next slab's writes
    }
#pragma unroll
    for (int nt = 0; nt < 4; ++nt) {
        const int gc = c0 + wc * 64 + nt * 16 + lr;
        const int i3 = gc >> 8, rem = gc & 255;
        const int h = rem >> 5, hd = rem & 31;
        const float bv = bias[gc];
        unsigned short* dst = (i3 == 0) ? qb : (i3 == 1) ? kb : vb;
#pragma unroll
        for (int mt = 0; mt < 4; ++mt)
#pragma unroll
            for (int j = 0; j < 4; ++j) {
                const int gr = r0 + wr * 64 + mt * 16 + lg * 4 + j;
                const int bb = gr >> 6, n = gr & 63;
                dst[(size_t)((bb * NHD + h) * NTOK + n) * HD + hd] =
                    (unsigned short)f2bf(acc[mt][nt][j] + bv);
            }
    }
}

// ------- proj GEMM via bf16 MFMA: 128x128 tile, BK=64, T14 prefetch -----------
__global__ __launch_bounds__(256) void k_proj_mfma(
    const unsigned short* __restrict__ A, const unsigned short* __restrict__ w,
    const float* __restrict__ bias, float* __restrict__ out) {
    __shared__ __align__(16) char As[128 * 128];
    __shared__ __align__(16) char Bs[128 * 128];
    const int t = threadIdx.x;
    const int bid = blockIdx.x;
    const int swz = (bid & 7) * (576 / 8) + (bid >> 3);
    const int r0 = (swz / 2) * 128;
    const int c0 = (swz % 2) * 128;
    const int wid = t >> 6, l = t & 63;
    const int wr = wid >> 1, wc = wid & 1;
    const int lr = l & 15, lg = l >> 4;
    f4_t acc[4][4] = {};
    bf8_t ra[4], rb_[4];
#pragma unroll
    for (int i = 0; i < 4; ++i) {
        const int u = t + 256 * i;
        const int row = u >> 3, c8 = u & 7;
        ra[i]  = *reinterpret_cast<const bf8_t*>(&A[(size_t)(r0 + row) * 256 + c8 * 8]);
        rb_[i] = *reinterpret_cast<const bf8_t*>(&w[(size_t)(c0 + row) * 256 + c8 * 8]);
    }
#pragma unroll 1
    for (int ks = 0; ks < 4; ++ks) {
#pragma unroll
        for (int i = 0; i < 4; ++i) {
            const int u = t + 256 * i;
            const int row = u >> 3, c8 = u & 7;
            *reinterpret_cast<bf8_t*>(As + row * 128 + ((c8 * 16) ^ ((row & 7) << 4))) = ra[i];
            *reinterpret_cast<bf8_t*>(Bs + row * 128 + ((c8 * 16) ^ ((row & 7) << 4))) = rb_[i];
        }
        __syncthreads();
        if (ks < 3) {
            const int k0n = (ks + 1) * 64;
#pragma unroll
            for (int i = 0; i < 4; ++i) {
                const int u = t + 256 * i;
                const int row = u >> 3, c8 = u & 7;
                ra[i]  = *reinterpret_cast<const bf8_t*>(&A[(size_t)(r0 + row) * 256 + k0n + c8 * 8]);
                rb_[i] = *reinterpret_cast<const bf8_t*>(&w[(size_t)(c0 + row) * 256 + k0n + c8 * 8]);
            }
        }
#pragma unroll
        for (int kk = 0; kk < 2; ++kk) {
            bf8_t a[4], b[4];
#pragma unroll
            for (int mt = 0; mt < 4; ++mt) {
                const int row = wr * 64 + mt * 16 + lr;
                a[mt] = *reinterpret_cast<const bf8_t*>(
                    As + row * 128 + ((kk * 64 + lg * 16) ^ ((row & 7) << 4)));
            }
#pragma unroll
            for (int nt = 0; nt < 4; ++nt) {
                const int row = wc * 64 + nt * 16 + lr;
                b[nt] = *reinterpret_cast<const bf8_t*>(
                    Bs + row * 128 + ((kk * 64 + lg * 16) ^ ((row & 7) << 4)));
            }
#pragma unroll
            for (int mt = 0; mt < 4; ++mt)
#pragma unroll
                for (int nt = 0; nt < 4; ++nt)
                    acc[mt][nt] = __builtin_amdgcn_mfma_f32_16x16x32_bf16(a[mt], b[nt], acc[mt][nt], 0, 0, 0);
        }
        __syncthreads();
    }
#pragma unroll
    for (int nt = 0; nt < 4; ++nt) {
        const int gc = c0 + wc * 64 + nt * 16 + lr;
        const float bv = bias[gc];
#pragma unroll
        for (int mt = 0; mt < 4; ++mt)
#pragma unroll
            for (int j = 0; j < 4; ++j) {
                const int gr = r0 + wr * 64 + mt * 16 + lg * 4 + j;
                out[(size_t)gr * 256 + gc] = acc[mt][nt][j] + bv;
            }
    }
}

// -------- ref scores, 1 block/window (all 8 h): q(bf16) . ref_q ---------------
// rs h-stride padded to 972 floats (972%32=12): conflict-free h-slots.
__global__ __launch_bounds__(256) void k_scores(
    const unsigned short* __restrict__ qbuf, const float* __restrict__ ref_q,
    float* __restrict__ scores) {
    const int bid = blockIdx.x;            // rb*NWIN + w
    const int w = bid % NWIN, rb = bid / NWIN;
    __shared__ __align__(16) float rs[8 * HSTRIDE];
    const int t = threadIdx.x;
    for (int u = t; u < 1920; u += 256) {
        const int off = u * 4;
        const int h = off / 960, rem = off % 960;
        *reinterpret_cast<float4*>(&rs[h * HSTRIDE + rem]) =
            *reinterpret_cast<const float4*>(&ref_q[(size_t)rb * 7680 + off]);
    }
    __syncthreads();
    const int h = t & 7, nb = t >> 3;      // nb 0..31
    const float* rsh = &rs[h * HSTRIDE];
#pragma unroll 1
    for (int half = 0; half < 2; ++half) {
        const int n = half * 32 + nb;
        const unsigned short* qsrc =
            &qbuf[(size_t)(((rb * NWIN + w) * NHD) + h) * 2048 + n * 32];
        float q[32];
#pragma unroll
        for (int c8 = 0; c8 < 4; ++c8) {
            bf8_t v = *reinterpret_cast<const bf8_t*>(&qsrc[c8 * 8]);
#pragma unroll
            for (int j = 0; j < 8; ++j)
                q[c8 * 8 + j] = bf2f((unsigned short)v[j]);
        }
        float* dst = &scores[((size_t)(rb * IMG_H + w * 64 + n) * NREF) * NHD + h];
        for (int r = 0; r < NREF; ++r) {
            float acc = 0.f;
#pragma unroll
            for (int d = 0; d < 32; ++d) acc += q[d] * rsh[r * 32 + d];
            dst[r * NHD] = acc;
        }
    }
}

// ---------------- conv 3x3 via MFMA (implicit GEMM), 32-row chunks ------------
// CHANNEL-LAST sc/upd: pixel (y,x) owns 8 contiguous channels.
template<int FUSED>
__global__ __launch_bounds__(256) void k_conv_mfma(
    const float* __restrict__ scPrev, const unsigned short* __restrict__ updPrev,
    const float* __restrict__ stPrev, const float* __restrict__ conv_w,
    const float* __restrict__ conv_b, float* __restrict__ scOut,
    unsigned short* __restrict__ updOut, float* __restrict__ stats) {
    const int bid = blockIdx.x;            // rb*288 + ychunk
    const int rb = bid / 288;
    const int y0 = (bid % 288) * 32;
    __shared__ __align__(16) unsigned short At[34][32][8];
    __shared__ float red[4][8][2];
    __shared__ float lmean[8], lrsig[8];
    const int t = threadIdx.x;
    if (FUSED) {
        if (t < 8) {
            const float s0 = stPrev[(rb * NHD + t) * 2];
            const float s1 = stPrev[(rb * NHD + t) * 2 + 1];
            const float m = s0 * (1.f / LN_CNT);
            const float v = s1 * (1.f / LN_CNT) - m * m;
            lmean[t] = m;
            lrsig[t] = rsqrtf(v + LN_EPS);
        }
        __syncthreads();
    }
    // zero pad columns sx = 0 and 31
    for (int f = t; f < 34 * 2; f += 256) {
        const int yy = f >> 1, side = (f & 1) ? 31 : 0;
        bf8_t z;
#pragma unroll
        for (int j = 0; j < 8; ++j) z[j] = 0;
        *reinterpret_cast<bf8_t*>(&At[yy][side][0]) = z;
    }
    // stage: pixel (yy, xc) -> 8 contiguous channels (32B) -> one b128 write
    for (int ps = t; ps < 34 * 30; ps += 256) {
        const int yy = ps / 30, xc = ps % 30;
        const int y = y0 - 1 + yy;
        bf8_t pk;
#pragma unroll
        for (int j = 0; j < 8; ++j) pk[j] = 0;
        if (y >= 0 && y < IMG_H) {
            const size_t idx = ((size_t)(rb * IMG_H + y) * NREF + xc) * NHD;
            float4 s0 = *reinterpret_cast<const float4*>(&scPrev[idx]);
            float4 s1 = *reinterpret_cast<const float4*>(&scPrev[idx + 4]);
            float a[8] = {s0.x, s0.y, s0.z, s0.w, s1.x, s1.y, s1.z, s1.w};
            if (FUSED) {
                bf8_t u8 = *reinterpret_cast<const bf8_t*>(&updPrev[idx]);
#pragma unroll
                for (int ci = 0; ci < 8; ++ci)
                    a[ci] += gelu_f((bf2f((unsigned short)u8[ci]) - lmean[ci]) * lrsig[ci]);
                if (yy >= 1 && yy <= 32) {
                    float4 o0, o1;
                    o0.x = a[0]; o0.y = a[1]; o0.z = a[2]; o0.w = a[3];
                    o1.x = a[4]; o1.y = a[5]; o1.z = a[6]; o1.w = a[7];
                    *reinterpret_cast<float4*>(&scOut[idx]) = o0;
                    *reinterpret_cast<float4*>(&scOut[idx + 4]) = o1;
                }
            }
#pragma unroll
            for (int ci = 0; ci < 8; ++ci) pk[ci] = f2bf(a[ci]);
        }
        *reinterpret_cast<bf8_t*>(&At[yy][xc + 1][0]) = pk;
    }
    // weight B-fragments: lane (lr=co, lg) holds k-slice [tap=kg*4+lg][ci 0..7]
    const int l = t & 63, wv = t >> 6;
    const int lr = l & 15, lg = l >> 4;
    bf8_t wf[3];
#pragma unroll
    for (int kg = 0; kg < 3; ++kg) {
        const int tap = kg * 4 + lg;
        bf8_t wq;
#pragma unroll
        for (int j = 0; j < 8; ++j) wq[j] = 0;
        if (lr < 8 && tap < 9) {
            const int dy = tap / 3, dx = tap % 3;
#pragma unroll
            for (int ci = 0; ci < 8; ++ci)
                wq[ci] = f2bf(conv_w[lr * 72 + ci * 9 + dy * 3 + dx]);
        }
        wf[kg] = wq;
    }
    const float cb = (lr < 8) ? conv_b[lr] : 0.f;
    __syncthreads();
    float ls = 0.f, lss = 0.f;
    // 60 M-tiles of 16 pixels; wave wv owns tiles [wv*15, wv*15+15)
#pragma unroll 1
    for (int ti = 0; ti < 15; ++ti) {
        const int tile = wv * 15 + ti;
        const int pA = tile * 16 + lr;     // A-side pixel for this lane
        const int ylA = pA / 30, xA = pA % 30;
        f4_t o;
        o[0] = cb; o[1] = cb; o[2] = cb; o[3] = cb;
#pragma unroll
        for (int kg = 0; kg < 3; ++kg) {
            const int tap = kg * 4 + lg;
            const int dy = (tap < 9) ? tap / 3 : 0;
            const int dx = (tap < 9) ? tap % 3 : 0;
            bf8_t a = *reinterpret_cast<const bf8_t*>(&At[ylA + dy][xA + dx][0]);
            o = __builtin_amdgcn_mfma_f32_16x16x32_bf16(a, wf[kg], o, 0, 0, 0);
        }
        if (lr < 8) {
#pragma unroll
            for (int j = 0; j < 4; ++j) {
                const int pD = tile * 16 + lg * 4 + j;
                const int yl = pD / 30, x = pD % 30;
                updOut[((size_t)(rb * IMG_H + y0 + yl) * NREF + x) * NHD + lr] =
                    (unsigned short)f2bf(o[j]);
                ls += o[j];
                lss += o[j] * o[j];
            }
        }
    }
    ls += __shfl_xor(ls, 16); ls += __shfl_xor(ls, 32);
    lss += __shfl_xor(lss, 16); lss += __shfl_xor(lss, 32);
    if (l < 8) { red[wv][l][0] = ls; red[wv][l][1] = lss; }
    __syncthreads();
    if (t < 8) {
        atomicAdd(&stats[(rb * NHD + t) * 2],
                  red[0][t][0] + red[1][t][0] + red[2][t][0] + red[3][t][0]);
        atomicAdd(&stats[(rb * NHD + t) * 2 + 1],
                  red[0][t][1] + red[1][t][1] + red[2][t][1] + red[3][t][1]);
    }
}

// --- softmax over NREF (fused final LN+gelu+residual), half-window blocks -----
// Round-26 streaming structure (48us, occ 32%) + cheap pass-1 bound:
// gelu(x) <= relu(x) <= gelu(x)+0.17, so ub = max(sc + relu(lin)) is a valid
// softmax shift (exp(val-ub) <= 1, within 0.17 of true max). Replaces 30 erf
// in pass 1 with 30 fma+max -- ~25% of kernel VALU removed, no extra LDS.
__global__ __launch_bounds__(256) void k_qnewf(
    const float* __restrict__ scores, const unsigned short* __restrict__ upd,
    const float* __restrict__ st, const float* __restrict__ ref_v,
    unsigned short* __restrict__ qbuf) {
    const int bid = blockIdx.x;            // (rb*NWIN + w)*2 + half
    const int half = bid & 1;
    const int wwin = (bid >> 1) % NWIN, rb = (bid >> 1) / NWIN;
    __shared__ __align__(16) float rv[8 * HSTRIDE];
    __shared__ float lmean[8], lrsig[8];
    const int t = threadIdx.x;
    if (t < 8) {
        const float s0 = st[(rb * NHD + t) * 2];
        const float s1 = st[(rb * NHD + t) * 2 + 1];
        const float m = s0 * (1.f / LN_CNT);
        const float v = s1 * (1.f / LN_CNT) - m * m;
        lmean[t] = m;
        lrsig[t] = rsqrtf(v + LN_EPS);
    }
    for (int u = t; u < 1920; u += 256) {
        const int off = u * 4;
        const int hh = off / 960, rem = off % 960;
        *reinterpret_cast<float4*>(&rv[hh * HSTRIDE + rem]) =
            *reinterpret_cast<const float4*>(&ref_v[(size_t)rb * 7680 + off]);
    }
    __syncthreads();
    const int h = t & 7, nb = t >> 3;
    const float lm = lmean[h], lr_ = lrsig[h];
    const float a1 = lr_, b1 = -lm * lr_;  // lin = fma(uv, a1, b1)
    const float* rvh = &rv[h * HSTRIDE];
    const int n = half * 32 + nb;
    const size_t base = ((size_t)(rb * IMG_H + wwin * 64 + n) * NREF) * NHD + h;
    // pass 1: upper bound via relu (no erf)
    float ub = -1e30f;
#pragma unroll 6
    for (int r = 0; r < NREF; ++r) {
        const float uv = bf2f(upd[base + r * NHD]);
        const float lin = fmaf(uv, a1, b1);
        ub = fmaxf(ub, scores[base + r * NHD] + fmaxf(lin, 0.f));
    }
    // pass 2: recompute val exactly (gelu once), accumulate (L2-resident reloads)
    float sum = 0.f;
    float acc[32] = {0.f};
#pragma unroll 2
    for (int r = 0; r < NREF; ++r) {
        const float uv = bf2f(upd[base + r * NHD]);
        const float val = scores[base + r * NHD] + gelu_f(fmaf(uv, a1, b1));
        const float e = expf(val - ub);
        sum += e;
#pragma unroll
        for (int d = 0; d < 32; ++d) acc[d] += e * rvh[r * 32 + d];
    }
    const float inv = SCALE / sum;
    unsigned short* dst =
        &qbuf[(size_t)(((rb * NWIN + wwin) * NHD) + h) * 2048 + n * 32];
#pragma unroll
    for (int c8 = 0; c8 < 4; ++c8) {
        bf8_t pk;
#pragma unroll
        for (int j = 0; j < 8; ++j) pk[j] = f2bf(acc[c8 * 8 + j] * inv);
        *reinterpret_cast<bf8_t*>(&dst[c8 * 8]) = pk;
    }
}

// ---------------- window attention via MFMA, swapped operands ----------------
__global__ __launch_bounds__(256, 4) void k_wattn_mfma(
    const unsigned short* __restrict__ qbuf, const unsigned short* __restrict__ kbuf,
    const unsigned short* __restrict__ vbuf, const float* __restrict__ bmt,
    unsigned short* __restrict__ pre) {
    const int wh = blockIdx.x;             // w*8 + h
    const int w = wh >> 3, h = wh & 7;
    const int t = threadIdx.x;
    const int rb = t >> 6;                 // wave id = rb
    const int l = t & 63;
    const int lr = l & 15, lg = l >> 4;
    const int b = rb * NWIN + w;
    const int bid = b * NHD + h;
    __shared__ __align__(16) char P[4][64 * 128];

    // ---- C init from bmt[w][h][m][n]
    f4_t acc[4][4];
    const float* bm = &bmt[(size_t)wh * 4096];
#pragma unroll
    for (int mt = 0; mt < 4; ++mt)
#pragma unroll
        for (int nt = 0; nt < 4; ++nt)
#pragma unroll
            for (int j = 0; j < 4; ++j)
                acc[mt][nt][j] = bm[(mt * 16 + lg * 4 + j) * 64 + nt * 16 + lr];

    // ---- K frags (A) and Q frags (B): both bf16, 8 contiguous
    const unsigned short* kp = &kbuf[(size_t)bid * 2048];
    const unsigned short* qp = &qbuf[(size_t)bid * 2048];
    bf8_t kf[4], qf[4];
#pragma unroll
    for (int mt = 0; mt < 4; ++mt) {
        kf[mt] = *reinterpret_cast<const bf8_t*>(&kp[(mt * 16 + lr) * 32 + lg * 8]);
        qf[mt] = *reinterpret_cast<const bf8_t*>(&qp[(mt * 16 + lr) * 32 + lg * 8]);
    }
    // ---- S^T[m][n] = sum_k k[m][kk] q[n][kk] + bm
#pragma unroll
    for (int mt = 0; mt < 4; ++mt)
#pragma unroll
        for (int nt = 0; nt < 4; ++nt)
            acc[mt][nt] = __builtin_amdgcn_mfma_f32_16x16x32_bf16(kf[mt], qf[nt], acc[mt][nt], 0, 0, 0);

    // ---- softmax over m (in-lane mt,j + shfl over lg)
#pragma unroll
    for (int nt = 0; nt < 4; ++nt) {
        float mx = -1e30f;
#pragma unroll
        for (int mt = 0; mt < 4; ++mt)
#pragma unroll
            for (int j = 0; j < 4; ++j) mx = fmaxf(mx, acc[mt][nt][j]);
        mx = fmaxf(mx, __shfl_xor(mx, 16));
        mx = fmaxf(mx, __shfl_xor(mx, 32));
        float s = 0.f;
#pragma unroll
        for (int mt = 0; mt < 4; ++mt)
#pragma unroll
            for (int j = 0; j < 4; ++j) {
                const float e = expf(acc[mt][nt][j] - mx);
                acc[mt][nt][j] = e;
                s += e;
            }
        s += __shfl_xor(s, 16);
        s += __shfl_xor(s, 32);
        const float inv = 1.f / s;
#pragma unroll
        for (int mt = 0; mt < 4; ++mt)
#pragma unroll
            for (int j = 0; j < 4; ++j) acc[mt][nt][j] *= inv;
    }

    // ---- pack P[n][m] bf16 into LDS (row 128B, XOR ((n&7)<<4))
    const int n7 = (lr & 7) << 4;
    char* Pw = P[rb];
#pragma unroll
    for (int nt = 0; nt < 4; ++nt) {
        const int rowb = (nt * 16 + lr) * 128;
#pragma unroll
        for (int mt = 0; mt < 4; ++mt)
#pragma unroll
            for (int jp = 0; jp < 2; ++jp) {
                const unsigned lo = (unsigned short)f2bf(acc[mt][nt][jp * 2]);
                const unsigned hi = (unsigned short)f2bf(acc[mt][nt][jp * 2 + 1]);
                const int mb = (mt * 16 + lg * 4 + jp * 2) * 2;
                *reinterpret_cast<unsigned*>(&Pw[rowb + (mb ^ n7)]) = lo | (hi << 16);
            }
    }
    __syncthreads();

    // ---- V^T frags (A): row hd, k = m (gather u16)
    const unsigned short* vp = &vbuf[(size_t)bid * 2048];
    bf8_t vf[2][2];
#pragma unroll
    for (int ht = 0; ht < 2; ++ht)
#pragma unroll
        for (int ks = 0; ks < 2; ++ks) {
            bf8_t tv;
#pragma unroll
            for (int j = 0; j < 8; ++j)
                tv[j] = (short)vp[(ks * 32 + lg * 8 + j) * 32 + ht * 16 + lr];
            vf[ht][ks] = tv;
        }

    // ---- O^T = V^T @ P^T
    f4_t o[2][4] = {};
#pragma unroll
    for (int ks = 0; ks < 2; ++ks)
#pragma unroll
        for (int nt = 0; nt < 4; ++nt) {
            const int rowb = (nt * 16 + lr) * 128;
            bf8_t pf = *reinterpret_cast<const bf8_t*>(&Pw[rowb + ((ks * 64 + lg * 16) ^ n7)]);
#pragma unroll
            for (int ht = 0; ht < 2; ++ht)
                o[ht][nt] = __builtin_amdgcn_mfma_f32_16x16x32_bf16(vf[ht][ks], pf, o[ht][nt], 0, 0, 0);
        }

    // ---- store O^T as bf16: pre[(b*64+n)*256 + h*32 + hd]
#pragma unroll
    for (int ht = 0; ht < 2; ++ht)
#pragma unroll
        for (int nt = 0; nt < 4; ++nt) {
            ushort4 pk;
            pk.x = (unsigned short)f2bf(o[ht][nt][0]);
            pk.y = (unsigned short)f2bf(o[ht][nt][1]);
            pk.z = (unsigned short)f2bf(o[ht][nt][2]);
            pk.w = (unsigned short)f2bf(o[ht][nt][3]);
            const int n = nt * 16 + lr;
            const int hd = ht * 16 + lg * 4;
            *reinterpret_cast<ushort4*>(&pre[(size_t)(b * 64 + n) * 256 + h * 32 + hd]) = pk;
        }
}

extern "C" void kernel_launch(void* const* d_in, const int* in_sizes, int n_in,
                              void* d_out, int out_size, void* d_ws, size_t ws_size,
                              hipStream_t stream) {
    const float* x          = (const float*)d_in[0];
    const float* mask       = (const float*)d_in[1];
    const float* x_ref      = (const float*)d_in[2];
    const float* qkv_w      = (const float*)d_in[3];
    const float* qkv_b      = (const float*)d_in[4];
    const float* proj_w     = (const float*)d_in[5];
    const float* proj_b     = (const float*)d_in[6];
    const float* bias_table = (const float*)d_in[7];
    const float* diff_mu    = (const float*)d_in[8];
    const float* diff_ls    = (const float*)d_in[9];
    const float* ref_qk_w   = (const float*)d_in[10];
    const float* ref_qk_b   = (const float*)d_in[11];
    const float* conv_w     = (const float*)d_in[12];
    const float* conv_b     = (const float*)d_in[13];
    const int*   rel_index  = (const int*)d_in[14];
    float* out = (float*)d_out;

    unsigned short* xb   = (unsigned short*)d_ws;                // 9437184 u16
    unsigned short* qb16 = xb + 9437184;                         // 9437184 u16
    unsigned short* kb16 = qb16 + 9437184;                       // 9437184 u16
    unsigned short* vb16 = kb16 + 9437184;                       // 9437184 u16
    float* scA           = (float*)(vb16 + 9437184);             // 8847360 f
    unsigned short* updA = (unsigned short*)(scA + 8847360);     // 8847360 u16
    unsigned short* updB = updA + 8847360;                       // 8847360 u16
    float* rq            = (float*)(updB + 8847360);             // 30720 f
    float* rv            = rq + 30720;                           // 30720 f
    float* st            = rv + 30720;                           // 192 f (3 x 64)
    float* bmt           = st + 192;                             // 4718592 f
    unsigned short* wqb  = (unsigned short*)(bmt + 4718592);     // 196608 u16
    unsigned short* wpb  = wqb + 196608;                         // 65536 u16
    float* scB           = (float*)d_ws;                         // reuses xb+qb16 (dead during conv)
    unsigned short* pre  = (unsigned short*)scA;                 // alias: scA dead after k_qnewf

    k_prep<<<2324, 256, 0, stream>>>(x, xb, qkv_w, wqb, proj_w, wpb,
                                     mask, bias_table, rel_index, bmt,
                                     x_ref, ref_qk_w, ref_qk_b, diff_mu, diff_ls,
                                     rq, rv);
    k_qkv_mfma<<<1728, 256, 0, stream>>>(xb, wqb, qkv_b, qb16, kb16, vb16);
    k_scores<<<RB * NWIN, 256, 0, stream>>>(qb16, rq, scA);
    hipMemsetAsync(st, 0, 192 * sizeof(float), stream);
    k_conv_mfma<0><<<RB * 288, 256, 0, stream>>>(scA, updA, st, conv_w, conv_b, scB, updA, st);
    k_conv_mfma<1><<<RB * 288, 256, 0, stream>>>(scA, updA, st, conv_w, conv_b, scB, updB, st + 64);
    k_conv_mfma<1><<<RB * 288, 256, 0, stream>>>(scB, updB, st + 64, conv_w, conv_b, scA, updA, st + 128);
    k_qnewf<<<RB * NWIN * 2, 256, 0, stream>>>(scA, updA, st + 128, rv, qb16);
    k_wattn_mfma<<<NWIN * NHD, 256, 0, stream>>>(qb16, kb16, vb16, bmt, pre);
    k_proj_mfma<<<576, 256, 0, stream>>>(pre, wpb, proj_b, out);
}

// Round 29
// 254.319 us; speedup vs baseline: 1.0596x; 1.0100x over previous
//
#include <hip/hip_runtime.h>
#include <math.h>

#define NHD 8
#define HD 32
#define NREF 30
#define RB 4
#define NWIN 144
#define NTOK 64
#define IMG_H (NWIN*NTOK)        /* 9216  */
#define LN_CNT (IMG_H*NREF)      /* 276480 */
#define SCALE 0.1767766952966369f
#define LN_EPS 1e-5f
#define HSTRIDE 972              /* 960 padded: 972%32=12 -> h-slots hit distinct banks */

typedef __attribute__((ext_vector_type(8))) short bf8_t;   // 8 x bf16
typedef __attribute__((ext_vector_type(4))) float f4_t;    // MFMA acc
typedef __attribute__((ext_vector_type(2))) float f2_t;    // packed fp32 pair

__device__ __forceinline__ float gelu_f(float v) {
    return 0.5f * v * (1.0f + erff(v * 0.7071067811865476f));
}

__device__ __forceinline__ short f2bf(float f) {           // fp32 -> bf16 RNE
    union { float f; unsigned u; } v; v.f = f;
    unsigned r = v.u + 0x7fffu + ((v.u >> 16) & 1u);
    return (short)(r >> 16);
}

__device__ __forceinline__ float bf2f(unsigned short u) {
    union { unsigned u; float f; } v; v.u = ((unsigned)u) << 16;
    return v.f;
}

// ---- fused prep: cvt(x) | bm | cvt(qkv_w) | cvt(proj_w) | refprep ----
__global__ __launch_bounds__(256) void k_prep(
    const float* __restrict__ x, unsigned short* __restrict__ xb,
    const float* __restrict__ qkv_w, unsigned short* __restrict__ wqb,
    const float* __restrict__ proj_w, unsigned short* __restrict__ wpb,
    const float* __restrict__ mask, const float* __restrict__ bias_table,
    const int* __restrict__ rel_index, float* __restrict__ bmt,
    const float* __restrict__ x_ref, const float* __restrict__ rw,
    const float* __restrict__ rbias, const float* __restrict__ dmu,
    const float* __restrict__ dls, float* __restrict__ ref_q,
    float* __restrict__ ref_v) {
    __shared__ float shbuf[4160 + 1800];   // bm: lm[64][65] + lb[1800]; refprep: 1864
    const int bid = blockIdx.x;
    const int t = threadIdx.x;
    if (bid < 2048) {                      // ---- cvt x (36MB -> 18MB)
        const int n8 = 9437184 / 8;
        for (int i = bid * 256 + t; i < n8; i += 2048 * 256) {
            const float* s = x + (size_t)i * 8;
            float4 a = *reinterpret_cast<const float4*>(s);
            float4 b = *reinterpret_cast<const float4*>(s + 4);
            bf8_t p;
            p[0] = f2bf(a.x); p[1] = f2bf(a.y); p[2] = f2bf(a.z); p[3] = f2bf(a.w);
            p[4] = f2bf(b.x); p[5] = f2bf(b.y); p[6] = f2bf(b.z); p[7] = f2bf(b.w);
            *reinterpret_cast<bf8_t*>(xb + (size_t)i * 8) = p;
        }
    } else if (bid < 2192) {               // ---- bm table (144 blocks, 1/window)
        const int w = bid - 2048;
        float* lm = shbuf;                 // [64][65] transposed-padded mask
        float* lb = shbuf + 4160;          // bias_table copy (225*8)
        for (int u = t; u < 4096; u += 256)
            lm[(u >> 6) * 65 + (u & 63)] = mask[(size_t)w * 4096 + u];
        for (int u = t; u < 1800; u += 256) lb[u] = bias_table[u];
        __syncthreads();
        for (int u = t; u < 4096; u += 256) {
            const int m = u >> 6, n = u & 63;
            const float mv = lm[n * 65 + m];
            const int ri = rel_index[n * 64 + m];
#pragma unroll
            for (int h = 0; h < 8; ++h)
                bmt[(size_t)(w * 8 + h) * 4096 + u] = mv + lb[ri * 8 + h];
        }
    } else if (bid < 2288) {               // ---- cvt qkv_w (96 blocks)
        const int b2 = bid - 2192;
        const int n8 = 196608 / 8;
        for (int i = b2 * 256 + t; i < n8; i += 96 * 256) {
            const float* s = qkv_w + (size_t)i * 8;
            float4 a = *reinterpret_cast<const float4*>(s);
            float4 b = *reinterpret_cast<const float4*>(s + 4);
            bf8_t p;
            p[0] = f2bf(a.x); p[1] = f2bf(a.y); p[2] = f2bf(a.z); p[3] = f2bf(a.w);
            p[4] = f2bf(b.x); p[5] = f2bf(b.y); p[6] = f2bf(b.z); p[7] = f2bf(b.w);
            *reinterpret_cast<bf8_t*>(wqb + (size_t)i * 8) = p;
        }
    } else if (bid < 2320) {               // ---- cvt proj_w (32 blocks)
        const int b2 = bid - 2288;
        const int n8 = 65536 / 8;
        for (int i = b2 * 256 + t; i < n8; i += 32 * 256) {
            const float* s = proj_w + (size_t)i * 8;
            float4 a = *reinterpret_cast<const float4*>(s);
            float4 b = *reinterpret_cast<const float4*>(s + 4);
            bf8_t p;
            p[0] = f2bf(a.x); p[1] = f2bf(a.y); p[2] = f2bf(a.z); p[3] = f2bf(a.w);
            p[4] = f2bf(b.x); p[5] = f2bf(b.y); p[6] = f2bf(b.z); p[7] = f2bf(b.w);
            *reinterpret_cast<bf8_t*>(wpb + (size_t)i * 8) = p;
        }
    } else {                               // ---- refprep (4 blocks)
        float* Wl = shbuf;                 // [60][NREF]
        float* Bl = shbuf + 60 * NREF;     // [60]
        const int rb = bid - 2320;
        for (int i = t; i < 60 * NREF; i += 256) Wl[i] = rw[i];
        if (t < 60) Bl[t] = rbias[t];
        __syncthreads();
        const int d = t;                   // 0..255
        float xr[NREF];
#pragma unroll
        for (int r = 0; r < NREF; ++r) xr[r] = x_ref[(rb * 256 + d) * NREF + r];
        const int h = d >> 5, hd = d & 31;
        const float mu = dmu[d], sg = expf(dls[d]);
        for (int j = 0; j < 60; ++j) {
            float acc = Bl[j];
#pragma unroll
            for (int r = 0; r < NREF; ++r) acc += xr[r] * Wl[j * NREF + r];
            if (j < NREF)
                ref_q[((rb * NHD + h) * NREF + j) * HD + hd] = mu + sg * acc;
            else
                ref_v[((rb * NHD + h) * NREF + (j - NREF)) * HD + hd] = acc;
        }
    }
}

// ------- qkv GEMM via bf16 MFMA: 128x128 tile, BK=64, T14 prefetch ------------
__global__ __launch_bounds__(256) void k_qkv_mfma(
    const unsigned short* __restrict__ xb, const unsigned short* __restrict__ wb,
    const float* __restrict__ bias, unsigned short* __restrict__ qb,
    unsigned short* __restrict__ kb, unsigned short* __restrict__ vb) {
    __shared__ __align__(16) char As[128 * 128];
    __shared__ __align__(16) char Bs[128 * 128];
    const int t = threadIdx.x;
    const int bid = blockIdx.x;
    const int swz = (bid & 7) * (1728 / 8) + (bid >> 3);
    const int r0 = (swz / 6) * 128;
    const int c0 = (swz % 6) * 128;
    const int wid = t >> 6, l = t & 63;
    const int wr = wid >> 1, wc = wid & 1;
    const int lr = l & 15, lg = l >> 4;
    f4_t acc[4][4] = {};
    bf8_t ra[4], rb_[4];
#pragma unroll
    for (int i = 0; i < 4; ++i) {
        const int u = t + 256 * i;
        const int row = u >> 3, c8 = u & 7;
        ra[i]  = *reinterpret_cast<const bf8_t*>(&xb[(size_t)(r0 + row) * 256 + c8 * 8]);
        rb_[i] = *reinterpret_cast<const bf8_t*>(&wb[(size_t)(c0 + row) * 256 + c8 * 8]);
    }
#pragma unroll 1
    for (int ks = 0; ks < 4; ++ks) {
#pragma unroll
        for (int i = 0; i < 4; ++i) {
            const int u = t + 256 * i;
            const int row = u >> 3, c8 = u & 7;
            *reinterpret_cast<bf8_t*>(As + row * 128 + ((c8 * 16) ^ ((row & 7) << 4))) = ra[i];
            *reinterpret_cast<bf8_t*>(Bs + row * 128 + ((c8 * 16) ^ ((row & 7) << 4))) = rb_[i];
        }
        __syncthreads();
        if (ks < 3) {
            const int k0n = (ks + 1) * 64;
#pragma unroll
            for (int i = 0; i < 4; ++i) {
                const int u = t + 256 * i;
                const int row = u >> 3, c8 = u & 7;
                ra[i]  = *reinterpret_cast<const bf8_t*>(&xb[(size_t)(r0 + row) * 256 + k0n + c8 * 8]);
                rb_[i] = *reinterpret_cast<const bf8_t*>(&wb[(size_t)(c0 + row) * 256 + k0n + c8 * 8]);
            }
        }
#pragma unroll
        for (int kk = 0; kk < 2; ++kk) {
            bf8_t a[4], b[4];
#pragma unroll
            for (int mt = 0; mt < 4; ++mt) {
                const int row = wr * 64 + mt * 16 + lr;
                a[mt] = *reinterpret_cast<const bf8_t*>(
                    As + row * 128 + ((kk * 64 + lg * 16) ^ ((row & 7) << 4)));
            }
#pragma unroll
            for (int nt = 0; nt < 4; ++nt) {
                const int row = wc * 64 + nt * 16 + lr;
                b[nt] = *reinterpret_cast<const bf8_t*>(
                    Bs + row * 128 + ((kk * 64 + lg * 16) ^ ((row & 7) << 4)));
            }
#pragma unroll
            for (int mt = 0; mt < 4; ++mt)
#pragma unroll
                for (int nt = 0; nt < 4; ++nt)
                    acc[mt][nt] = __builtin_amdgcn_mfma_f32_16x16x32_bf16(a[mt], b[nt], acc[mt][nt], 0, 0, 0);
        }
        __syncthreads();                   // reads done before next slab's writes
    }
#pragma unroll
    for (int nt = 0; nt < 4; ++nt) {
        const int gc = c0 + wc * 64 + nt * 16 + lr;
        const int i3 = gc >> 8, rem = gc & 255;
        const int h = rem >> 5, hd = rem & 31;
        const float bv = bias[gc];
        unsigned short* dst = (i3 == 0) ? qb : (i3 == 1) ? kb : vb;
#pragma unroll
        for (int mt = 0; mt < 4; ++mt)
#pragma unroll
            for (int j = 0; j < 4; ++j) {
                const int gr = r0 + wr * 64 + mt * 16 + lg * 4 + j;
                const int bb = gr >> 6, n = gr & 63;
                dst[(size_t)((bb * NHD + h) * NTOK + n) * HD + hd] =
                    (unsigned short)f2bf(acc[mt][nt][j] + bv);
            }
    }
}

// ------- proj GEMM via bf16 MFMA: 128x128 tile, BK=64, T14 prefetch -----------
__global__ __launch_bounds__(256) void k_proj_mfma(
    const unsigned short* __restrict__ A, const unsigned short* __restrict__ w,
    const float* __restrict__ bias, float* __restrict__ out) {
    __shared__ __align__(16) char As[128 * 128];
    __shared__ __align__(16) char Bs[128 * 128];
    const int t = threadIdx.x;
    const int bid = blockIdx.x;
    const int swz = (bid & 7) * (576 / 8) + (bid >> 3);
    const int r0 = (swz / 2) * 128;
    const int c0 = (swz % 2) * 128;
    const int wid = t >> 6, l = t & 63;
    const int wr = wid >> 1, wc = wid & 1;
    const int lr = l & 15, lg = l >> 4;
    f4_t acc[4][4] = {};
    bf8_t ra[4], rb_[4];
#pragma unroll
    for (int i = 0; i < 4; ++i) {
        const int u = t + 256 * i;
        const int row = u >> 3, c8 = u & 7;
        ra[i]  = *reinterpret_cast<const bf8_t*>(&A[(size_t)(r0 + row) * 256 + c8 * 8]);
        rb_[i] = *reinterpret_cast<const bf8_t*>(&w[(size_t)(c0 + row) * 256 + c8 * 8]);
    }
#pragma unroll 1
    for (int ks = 0; ks < 4; ++ks) {
#pragma unroll
        for (int i = 0; i < 4; ++i) {
            const int u = t + 256 * i;
            const int row = u >> 3, c8 = u & 7;
            *reinterpret_cast<bf8_t*>(As + row * 128 + ((c8 * 16) ^ ((row & 7) << 4))) = ra[i];
            *reinterpret_cast<bf8_t*>(Bs + row * 128 + ((c8 * 16) ^ ((row & 7) << 4))) = rb_[i];
        }
        __syncthreads();
        if (ks < 3) {
            const int k0n = (ks + 1) * 64;
#pragma unroll
            for (int i = 0; i < 4; ++i) {
                const int u = t + 256 * i;
                const int row = u >> 3, c8 = u & 7;
                ra[i]  = *reinterpret_cast<const bf8_t*>(&A[(size_t)(r0 + row) * 256 + k0n + c8 * 8]);
                rb_[i] = *reinterpret_cast<const bf8_t*>(&w[(size_t)(c0 + row) * 256 + k0n + c8 * 8]);
            }
        }
#pragma unroll
        for (int kk = 0; kk < 2; ++kk) {
            bf8_t a[4], b[4];
#pragma unroll
            for (int mt = 0; mt < 4; ++mt) {
                const int row = wr * 64 + mt * 16 + lr;
                a[mt] = *reinterpret_cast<const bf8_t*>(
                    As + row * 128 + ((kk * 64 + lg * 16) ^ ((row & 7) << 4)));
            }
#pragma unroll
            for (int nt = 0; nt < 4; ++nt) {
                const int row = wc * 64 + nt * 16 + lr;
                b[nt] = *reinterpret_cast<const bf8_t*>(
                    Bs + row * 128 + ((kk * 64 + lg * 16) ^ ((row & 7) << 4)));
            }
#pragma unroll
            for (int mt = 0; mt < 4; ++mt)
#pragma unroll
                for (int nt = 0; nt < 4; ++nt)
                    acc[mt][nt] = __builtin_amdgcn_mfma_f32_16x16x32_bf16(a[mt], b[nt], acc[mt][nt], 0, 0, 0);
        }
        __syncthreads();
    }
#pragma unroll
    for (int nt = 0; nt < 4; ++nt) {
        const int gc = c0 + wc * 64 + nt * 16 + lr;
        const float bv = bias[gc];
#pragma unroll
        for (int mt = 0; mt < 4; ++mt)
#pragma unroll
            for (int j = 0; j < 4; ++j) {
                const int gr = r0 + wr * 64 + mt * 16 + lg * 4 + j;
                out[(size_t)gr * 256 + gc] = acc[mt][nt][j] + bv;
            }
    }
}

// -------- ref scores, 1 block/window (all 8 h): q(bf16) . ref_q ---------------
// rs h-stride padded to 972 floats (972%32=12): conflict-free h-slots.
__global__ __launch_bounds__(256) void k_scores(
    const unsigned short* __restrict__ qbuf, const float* __restrict__ ref_q,
    float* __restrict__ scores) {
    const int bid = blockIdx.x;            // rb*NWIN + w
    const int w = bid % NWIN, rb = bid / NWIN;
    __shared__ __align__(16) float rs[8 * HSTRIDE];
    const int t = threadIdx.x;
    for (int u = t; u < 1920; u += 256) {
        const int off = u * 4;
        const int h = off / 960, rem = off % 960;
        *reinterpret_cast<float4*>(&rs[h * HSTRIDE + rem]) =
            *reinterpret_cast<const float4*>(&ref_q[(size_t)rb * 7680 + off]);
    }
    __syncthreads();
    const int h = t & 7, nb = t >> 3;      // nb 0..31
    const float* rsh = &rs[h * HSTRIDE];
#pragma unroll 1
    for (int half = 0; half < 2; ++half) {
        const int n = half * 32 + nb;
        const unsigned short* qsrc =
            &qbuf[(size_t)(((rb * NWIN + w) * NHD) + h) * 2048 + n * 32];
        float q[32];
#pragma unroll
        for (int c8 = 0; c8 < 4; ++c8) {
            bf8_t v = *reinterpret_cast<const bf8_t*>(&qsrc[c8 * 8]);
#pragma unroll
            for (int j = 0; j < 8; ++j)
                q[c8 * 8 + j] = bf2f((unsigned short)v[j]);
        }
        float* dst = &scores[((size_t)(rb * IMG_H + w * 64 + n) * NREF) * NHD + h];
        for (int r = 0; r < NREF; ++r) {
            float acc = 0.f;
#pragma unroll
            for (int d = 0; d < 32; ++d) acc += q[d] * rsh[r * 32 + d];
            dst[r * NHD] = acc;
        }
    }
}

// ---------------- conv 3x3 via MFMA (implicit GEMM), 32-row chunks ------------
// CHANNEL-LAST sc/upd: pixel (y,x) owns 8 contiguous channels.
template<int FUSED>
__global__ __launch_bounds__(256) void k_conv_mfma(
    const float* __restrict__ scPrev, const unsigned short* __restrict__ updPrev,
    const float* __restrict__ stPrev, const float* __restrict__ conv_w,
    const float* __restrict__ conv_b, float* __restrict__ scOut,
    unsigned short* __restrict__ updOut, float* __restrict__ stats) {
    const int bid = blockIdx.x;            // rb*288 + ychunk
    const int rb = bid / 288;
    const int y0 = (bid % 288) * 32;
    __shared__ __align__(16) unsigned short At[34][32][8];
    __shared__ float red[4][8][2];
    __shared__ float lmean[8], lrsig[8];
    const int t = threadIdx.x;
    if (FUSED) {
        if (t < 8) {
            const float s0 = stPrev[(rb * NHD + t) * 2];
            const float s1 = stPrev[(rb * NHD + t) * 2 + 1];
            const float m = s0 * (1.f / LN_CNT);
            const float v = s1 * (1.f / LN_CNT) - m * m;
            lmean[t] = m;
            lrsig[t] = rsqrtf(v + LN_EPS);
        }
        __syncthreads();
    }
    // zero pad columns sx = 0 and 31
    for (int f = t; f < 34 * 2; f += 256) {
        const int yy = f >> 1, side = (f & 1) ? 31 : 0;
        bf8_t z;
#pragma unroll
        for (int j = 0; j < 8; ++j) z[j] = 0;
        *reinterpret_cast<bf8_t*>(&At[yy][side][0]) = z;
    }
    // stage: pixel (yy, xc) -> 8 contiguous channels (32B) -> one b128 write
    for (int ps = t; ps < 34 * 30; ps += 256) {
        const int yy = ps / 30, xc = ps % 30;
        const int y = y0 - 1 + yy;
        bf8_t pk;
#pragma unroll
        for (int j = 0; j < 8; ++j) pk[j] = 0;
        if (y >= 0 && y < IMG_H) {
            const size_t idx = ((size_t)(rb * IMG_H + y) * NREF + xc) * NHD;
            float4 s0 = *reinterpret_cast<const float4*>(&scPrev[idx]);
            float4 s1 = *reinterpret_cast<const float4*>(&scPrev[idx + 4]);
            float a[8] = {s0.x, s0.y, s0.z, s0.w, s1.x, s1.y, s1.z, s1.w};
            if (FUSED) {
                bf8_t u8 = *reinterpret_cast<const bf8_t*>(&updPrev[idx]);
#pragma unroll
                for (int ci = 0; ci < 8; ++ci)
                    a[ci] += gelu_f((bf2f((unsigned short)u8[ci]) - lmean[ci]) * lrsig[ci]);
                if (yy >= 1 && yy <= 32) {
                    float4 o0, o1;
                    o0.x = a[0]; o0.y = a[1]; o0.z = a[2]; o0.w = a[3];
                    o1.x = a[4]; o1.y = a[5]; o1.z = a[6]; o1.w = a[7];
                    *reinterpret_cast<float4*>(&scOut[idx]) = o0;
                    *reinterpret_cast<float4*>(&scOut[idx + 4]) = o1;
                }
            }
#pragma unroll
            for (int ci = 0; ci < 8; ++ci) pk[ci] = f2bf(a[ci]);
        }
        *reinterpret_cast<bf8_t*>(&At[yy][xc + 1][0]) = pk;
    }
    // weight B-fragments: lane (lr=co, lg) holds k-slice [tap=kg*4+lg][ci 0..7]
    const int l = t & 63, wv = t >> 6;
    const int lr = l & 15, lg = l >> 4;
    bf8_t wf[3];
#pragma unroll
    for (int kg = 0; kg < 3; ++kg) {
        const int tap = kg * 4 + lg;
        bf8_t wq;
#pragma unroll
        for (int j = 0; j < 8; ++j) wq[j] = 0;
        if (lr < 8 && tap < 9) {
            const int dy = tap / 3, dx = tap % 3;
#pragma unroll
            for (int ci = 0; ci < 8; ++ci)
                wq[ci] = f2bf(conv_w[lr * 72 + ci * 9 + dy * 3 + dx]);
        }
        wf[kg] = wq;
    }
    const float cb = (lr < 8) ? conv_b[lr] : 0.f;
    __syncthreads();
    float ls = 0.f, lss = 0.f;
    // 60 M-tiles of 16 pixels; wave wv owns tiles [wv*15, wv*15+15)
#pragma unroll 1
    for (int ti = 0; ti < 15; ++ti) {
        const int tile = wv * 15 + ti;
        const int pA = tile * 16 + lr;     // A-side pixel for this lane
        const int ylA = pA / 30, xA = pA % 30;
        f4_t o;
        o[0] = cb; o[1] = cb; o[2] = cb; o[3] = cb;
#pragma unroll
        for (int kg = 0; kg < 3; ++kg) {
            const int tap = kg * 4 + lg;
            const int dy = (tap < 9) ? tap / 3 : 0;
            const int dx = (tap < 9) ? tap % 3 : 0;
            bf8_t a = *reinterpret_cast<const bf8_t*>(&At[ylA + dy][xA + dx][0]);
            o = __builtin_amdgcn_mfma_f32_16x16x32_bf16(a, wf[kg], o, 0, 0, 0);
        }
        if (lr < 8) {
#pragma unroll
            for (int j = 0; j < 4; ++j) {
                const int pD = tile * 16 + lg * 4 + j;
                const int yl = pD / 30, x = pD % 30;
                updOut[((size_t)(rb * IMG_H + y0 + yl) * NREF + x) * NHD + lr] =
                    (unsigned short)f2bf(o[j]);
                ls += o[j];
                lss += o[j] * o[j];
            }
        }
    }
    ls += __shfl_xor(ls, 16); ls += __shfl_xor(ls, 32);
    lss += __shfl_xor(lss, 16); lss += __shfl_xor(lss, 32);
    if (l < 8) { red[wv][l][0] = ls; red[wv][l][1] = lss; }
    __syncthreads();
    if (t < 8) {
        atomicAdd(&stats[(rb * NHD + t) * 2],
                  red[0][t][0] + red[1][t][0] + red[2][t][0] + red[3][t][0]);
        atomicAdd(&stats[(rb * NHD + t) * 2 + 1],
                  red[0][t][1] + red[1][t][1] + red[2][t][1] + red[3][t][1]);
    }
}

// --- softmax over NREF (fused final LN+gelu+residual), half-window blocks -----
// Streaming two-pass + relu upper bound (round 28). This round: packed f32
// pairs for the 30x32 accumulate (f2_t -> v_pk_fma_f32, halves FMA+ds_read
// instruction count, numerics identical) and __expf (v_exp_f32).
__global__ __launch_bounds__(256) void k_qnewf(
    const float* __restrict__ scores, const unsigned short* __restrict__ upd,
    const float* __restrict__ st, const float* __restrict__ ref_v,
    unsigned short* __restrict__ qbuf) {
    const int bid = blockIdx.x;            // (rb*NWIN + w)*2 + half
    const int half = bid & 1;
    const int wwin = (bid >> 1) % NWIN, rb = (bid >> 1) / NWIN;
    __shared__ __align__(16) float rv[8 * HSTRIDE];
    __shared__ float lmean[8], lrsig[8];
    const int t = threadIdx.x;
    if (t < 8) {
        const float s0 = st[(rb * NHD + t) * 2];
        const float s1 = st[(rb * NHD + t) * 2 + 1];
        const float m = s0 * (1.f / LN_CNT);
        const float v = s1 * (1.f / LN_CNT) - m * m;
        lmean[t] = m;
        lrsig[t] = rsqrtf(v + LN_EPS);
    }
    for (int u = t; u < 1920; u += 256) {
        const int off = u * 4;
        const int hh = off / 960, rem = off % 960;
        *reinterpret_cast<float4*>(&rv[hh * HSTRIDE + rem]) =
            *reinterpret_cast<const float4*>(&ref_v[(size_t)rb * 7680 + off]);
    }
    __syncthreads();
    const int h = t & 7, nb = t >> 3;
    const float lm = lmean[h], lr_ = lrsig[h];
    const float a1 = lr_, b1 = -lm * lr_;  // lin = fma(uv, a1, b1)
    const float* rvh = &rv[h * HSTRIDE];
    const int n = half * 32 + nb;
    const size_t base = ((size_t)(rb * IMG_H + wwin * 64 + n) * NREF) * NHD + h;
    // pass 1: upper bound via relu (no erf)
    float ub = -1e30f;
#pragma unroll 6
    for (int r = 0; r < NREF; ++r) {
        const float uv = bf2f(upd[base + r * NHD]);
        const float lin = fmaf(uv, a1, b1);
        ub = fmaxf(ub, scores[base + r * NHD] + fmaxf(lin, 0.f));
    }
    // pass 2: gelu once, packed-pair accumulate (L2-resident reloads)
    float sum = 0.f;
    f2_t acc2[16] = {};
#pragma unroll 2
    for (int r = 0; r < NREF; ++r) {
        const float uv = bf2f(upd[base + r * NHD]);
        const float val = scores[base + r * NHD] + gelu_f(fmaf(uv, a1, b1));
        const float e = __expf(val - ub);
        sum += e;
        f2_t e2; e2[0] = e; e2[1] = e;
        const f2_t* rv2 = reinterpret_cast<const f2_t*>(&rvh[r * 32]);
#pragma unroll
        for (int d2 = 0; d2 < 16; ++d2) acc2[d2] += e2 * rv2[d2];
    }
    const float inv = SCALE / sum;
    const float* accf = reinterpret_cast<const float*>(acc2);
    unsigned short* dst =
        &qbuf[(size_t)(((rb * NWIN + wwin) * NHD) + h) * 2048 + n * 32];
#pragma unroll
    for (int c8 = 0; c8 < 4; ++c8) {
        bf8_t pk;
#pragma unroll
        for (int j = 0; j < 8; ++j) pk[j] = f2bf(accf[c8 * 8 + j] * inv);
        *reinterpret_cast<bf8_t*>(&dst[c8 * 8]) = pk;
    }
}

// ---------------- window attention via MFMA, swapped operands ----------------
__global__ __launch_bounds__(256, 4) void k_wattn_mfma(
    const unsigned short* __restrict__ qbuf, const unsigned short* __restrict__ kbuf,
    const unsigned short* __restrict__ vbuf, const float* __restrict__ bmt,
    unsigned short* __restrict__ pre) {
    const int wh = blockIdx.x;             // w*8 + h
    const int w = wh >> 3, h = wh & 7;
    const int t = threadIdx.x;
    const int rb = t >> 6;                 // wave id = rb
    const int l = t & 63;
    const int lr = l & 15, lg = l >> 4;
    const int b = rb * NWIN + w;
    const int bid = b * NHD + h;
    __shared__ __align__(16) char P[4][64 * 128];

    // ---- C init from bmt[w][h][m][n]
    f4_t acc[4][4];
    const float* bm = &bmt[(size_t)wh * 4096];
#pragma unroll
    for (int mt = 0; mt < 4; ++mt)
#pragma unroll
        for (int nt = 0; nt < 4; ++nt)
#pragma unroll
            for (int j = 0; j < 4; ++j)
                acc[mt][nt][j] = bm[(mt * 16 + lg * 4 + j) * 64 + nt * 16 + lr];

    // ---- K frags (A) and Q frags (B): both bf16, 8 contiguous
    const unsigned short* kp = &kbuf[(size_t)bid * 2048];
    const unsigned short* qp = &qbuf[(size_t)bid * 2048];
    bf8_t kf[4], qf[4];
#pragma unroll
    for (int mt = 0; mt < 4; ++mt) {
        kf[mt] = *reinterpret_cast<const bf8_t*>(&kp[(mt * 16 + lr) * 32 + lg * 8]);
        qf[mt] = *reinterpret_cast<const bf8_t*>(&qp[(mt * 16 + lr) * 32 + lg * 8]);
    }
    // ---- S^T[m][n] = sum_k k[m][kk] q[n][kk] + bm
#pragma unroll
    for (int mt = 0; mt < 4; ++mt)
#pragma unroll
        for (int nt = 0; nt < 4; ++nt)
            acc[mt][nt] = __builtin_amdgcn_mfma_f32_16x16x32_bf16(kf[mt], qf[nt], acc[mt][nt], 0, 0, 0);

    // ---- softmax over m (in-lane mt,j + shfl over lg)
#pragma unroll
    for (int nt = 0; nt < 4; ++nt) {
        float mx = -1e30f;
#pragma unroll
        for (int mt = 0; mt < 4; ++mt)
#pragma unroll
            for (int j = 0; j < 4; ++j) mx = fmaxf(mx, acc[mt][nt][j]);
        mx = fmaxf(mx, __shfl_xor(mx, 16));
        mx = fmaxf(mx, __shfl_xor(mx, 32));
        float s = 0.f;
#pragma unroll
        for (int mt = 0; mt < 4; ++mt)
#pragma unroll
            for (int j = 0; j < 4; ++j) {
                const float e = __expf(acc[mt][nt][j] - mx);
                acc[mt][nt][j] = e;
                s += e;
            }
        s += __shfl_xor(s, 16);
        s += __shfl_xor(s, 32);
        const float inv = 1.f / s;
#pragma unroll
        for (int mt = 0; mt < 4; ++mt)
#pragma unroll
            for (int j = 0; j < 4; ++j) acc[mt][nt][j] *= inv;
    }

    // ---- pack P[n][m] bf16 into LDS (row 128B, XOR ((n&7)<<4))
    const int n7 = (lr & 7) << 4;
    char* Pw = P[rb];
#pragma unroll
    for (int nt = 0; nt < 4; ++nt) {
        const int rowb = (nt * 16 + lr) * 128;
#pragma unroll
        for (int mt = 0; mt < 4; ++mt)
#pragma unroll
            for (int jp = 0; jp < 2; ++jp) {
                const unsigned lo = (unsigned short)f2bf(acc[mt][nt][jp * 2]);
                const unsigned hi = (unsigned short)f2bf(acc[mt][nt][jp * 2 + 1]);
                const int mb = (mt * 16 + lg * 4 + jp * 2) * 2;
                *reinterpret_cast<unsigned*>(&Pw[rowb + (mb ^ n7)]) = lo | (hi << 16);
            }
    }
    __syncthreads();

    // ---- V^T frags (A): row hd, k = m (gather u16)
    const unsigned short* vp = &vbuf[(size_t)bid * 2048];
    bf8_t vf[2][2];
#pragma unroll
    for (int ht = 0; ht < 2; ++ht)
#pragma unroll
        for (int ks = 0; ks < 2; ++ks) {
            bf8_t tv;
#pragma unroll
            for (int j = 0; j < 8; ++j)
                tv[j] = (short)vp[(ks * 32 + lg * 8 + j) * 32 + ht * 16 + lr];
            vf[ht][ks] = tv;
        }

    // ---- O^T = V^T @ P^T
    f4_t o[2][4] = {};
#pragma unroll
    for (int ks = 0; ks < 2; ++ks)
#pragma unroll
        for (int nt = 0; nt < 4; ++nt) {
            const int rowb = (nt * 16 + lr) * 128;
            bf8_t pf = *reinterpret_cast<const bf8_t*>(&Pw[rowb + ((ks * 64 + lg * 16) ^ n7)]);
#pragma unroll
            for (int ht = 0; ht < 2; ++ht)
                o[ht][nt] = __builtin_amdgcn_mfma_f32_16x16x32_bf16(vf[ht][ks], pf, o[ht][nt], 0, 0, 0);
        }

    // ---- store O^T as bf16: pre[(b*64+n)*256 + h*32 + hd]
#pragma unroll
    for (int ht = 0; ht < 2; ++ht)
#pragma unroll
        for (int nt = 0; nt < 4; ++nt) {
            ushort4 pk;
            pk.x = (unsigned short)f2bf(o[ht][nt][0]);
            pk.y = (unsigned short)f2bf(o[ht][nt][1]);
            pk.z = (unsigned short)f2bf(o[ht][nt][2]);
            pk.w = (unsigned short)f2bf(o[ht][nt][3]);
            const int n = nt * 16 + lr;
            const int hd = ht * 16 + lg * 4;
            *reinterpret_cast<ushort4*>(&pre[(size_t)(b * 64 + n) * 256 + h * 32 + hd]) = pk;
        }
}

extern "C" void kernel_launch(void* const* d_in, const int* in_sizes, int n_in,
                              void* d_out, int out_size, void* d_ws, size_t ws_size,
                              hipStream_t stream) {
    const float* x          = (const float*)d_in[0];
    const float* mask       = (const float*)d_in[1];
    const float* x_ref      = (const float*)d_in[2];
    const float* qkv_w      = (const float*)d_in[3];
    const float* qkv_b      = (const float*)d_in[4];
    const float* proj_w     = (const float*)d_in[5];
    const float* proj_b     = (const float*)d_in[6];
    const float* bias_table = (const float*)d_in[7];
    const float* diff_mu    = (const float*)d_in[8];
    const float* diff_ls    = (const float*)d_in[9];
    const float* ref_qk_w   = (const float*)d_in[10];
    const float* ref_qk_b   = (const float*)d_in[11];
    const float* conv_w     = (const float*)d_in[12];
    const float* conv_b     = (const float*)d_in[13];
    const int*   rel_index  = (const int*)d_in[14];
    float* out = (float*)d_out;

    unsigned short* xb   = (unsigned short*)d_ws;                // 9437184 u16
    unsigned short* qb16 = xb + 9437184;                         // 9437184 u16
    unsigned short* kb16 = qb16 + 9437184;                       // 9437184 u16
    unsigned short* vb16 = kb16 + 9437184;                       // 9437184 u16
    float* scA           = (float*)(vb16 + 9437184);             // 8847360 f
    unsigned short* updA = (unsigned short*)(scA + 8847360);     // 8847360 u16
    unsigned short* updB = updA + 8847360;                       // 8847360 u16
    float* rq            = (float*)(updB + 8847360);             // 30720 f
    float* rv            = rq + 30720;                           // 30720 f
    float* st            = rv + 30720;                           // 192 f (3 x 64)
    float* bmt           = st + 192;                             // 4718592 f
    unsigned short* wqb  = (unsigned short*)(bmt + 4718592);     // 196608 u16
    unsigned short* wpb  = wqb + 196608;                         // 65536 u16
    float* scB           = (float*)d_ws;                         // reuses xb+qb16 (dead during conv)
    unsigned short* pre  = (unsigned short*)scA;                 // alias: scA dead after k_qnewf

    k_prep<<<2324, 256, 0, stream>>>(x, xb, qkv_w, wqb, proj_w, wpb,
                                     mask, bias_table, rel_index, bmt,
                                     x_ref, ref_qk_w, ref_qk_b, diff_mu, diff_ls,
                                     rq, rv);
    k_qkv_mfma<<<1728, 256, 0, stream>>>(xb, wqb, qkv_b, qb16, kb16, vb16);
    k_scores<<<RB * NWIN, 256, 0, stream>>>(qb16, rq, scA);
    hipMemsetAsync(st, 0, 192 * sizeof(float), stream);
    k_conv_mfma<0><<<RB * 288, 256, 0, stream>>>(scA, updA, st, conv_w, conv_b, scB, updA, st);
    k_conv_mfma<1><<<RB * 288, 256, 0, stream>>>(scA, updA, st, conv_w, conv_b, scB, updB, st + 64);
    k_conv_mfma<1><<<RB * 288, 256, 0, stream>>>(scB, updB, st + 64, conv_w, conv_b, scA, updA, st + 128);
    k_qnewf<<<RB * NWIN * 2, 256, 0, stream>>>(scA, updA, st + 128, rv, qb16);
    k_wattn_mfma<<<NWIN * NHD, 256, 0, stream>>>(qb16, kb16, vb16, bmt, pre);
    k_proj_mfma<<<576, 256, 0, stream>>>(pre, wpb, proj_b, out);
}